// Round 8
// baseline (270.926 us; speedup 1.0000x reference)
//
#include <hip/hip_runtime.h>

// Problem constants: x [B=2, C=512, H=64, W=64], 32 groups, N = H*W = 4096.
#define BB 2
#define CC 512
#define NS 4096
#define NGROUP 32
#define TILE 128
#define RSTRIDE 132   // repack LDS row stride (floats): 128 + 4 pad

typedef __bf16 bf16_8 __attribute__((ext_vector_type(8)));
typedef __bf16 bf16_4 __attribute__((ext_vector_type(4)));
typedef float f32_4 __attribute__((ext_vector_type(4)));

#define SMEM_BYTES 65536   // BK=128 staging: A 32KB + B 32KB (repack unions into it)

__device__ __forceinline__ void gld_lds16(const __bf16* g, __bf16* l) {
  __builtin_amdgcn_global_load_lds(
      (const __attribute__((address_space(1))) unsigned int*)g,
      (__attribute__((address_space(3))) unsigned int*)l, 16, 0, 0);
}

// ---------------- GroupNorm ----------------
__global__ __launch_bounds__(256) void gn_stats(const float* __restrict__ x,
                                                float* __restrict__ stats) {
  const float4* p = (const float4*)(x + (size_t)blockIdx.x * 65536);
  float s = 0.f, q = 0.f;
  for (int i = threadIdx.x; i < 16384; i += 256) {
    float4 v = p[i];
    s += v.x + v.y + v.z + v.w;
    q += v.x * v.x + v.y * v.y + v.z * v.z + v.w * v.w;
  }
#pragma unroll
  for (int off = 32; off > 0; off >>= 1) {
    s += __shfl_down(s, off, 64);
    q += __shfl_down(q, off, 64);
  }
  __shared__ float ls[4], lq[4];
  int wave = threadIdx.x >> 6, lane = threadIdx.x & 63;
  if (lane == 0) { ls[wave] = s; lq[wave] = q; }
  __syncthreads();
  if (threadIdx.x == 0) {
    float S = ls[0] + ls[1] + ls[2] + ls[3];
    float Q = lq[0] + lq[1] + lq[2] + lq[3];
    float mean = S * (1.f / 65536.f);
    float var = Q * (1.f / 65536.f) - mean * mean;
    stats[blockIdx.x * 2] = mean;
    stats[blockIdx.x * 2 + 1] = rsqrtf(var + 1e-6f);
  }
}

// Normalize + transpose: x[b][c][n] (fp32) -> hnT[b][n][c] (bf16), 32x32 tiles via LDS.
__global__ __launch_bounds__(256) void gn_apply_t(const float* __restrict__ x,
                                                  const float* __restrict__ stats,
                                                  const float* __restrict__ gamma,
                                                  const float* __restrict__ beta,
                                                  __bf16* __restrict__ hnT) {
  __shared__ float tile[32][33];
  int b = blockIdx.z;
  int c0 = blockIdx.y * 32;
  int n0 = blockIdx.x * 32;
  int tx = threadIdx.x;  // 0..31
  int ty = threadIdx.y;  // 0..7
  const float* xb = x + (size_t)b * CC * NS;
#pragma unroll
  for (int i = 0; i < 4; i++) {
    int c = c0 + ty + i * 8;
    float mean = stats[(b * NGROUP + (c >> 4)) * 2 + 0];
    float rstd = stats[(b * NGROUP + (c >> 4)) * 2 + 1];
    float v = xb[(size_t)c * NS + n0 + tx];
    tile[ty + i * 8][tx] = (v - mean) * rstd * gamma[c] + beta[c];
  }
  __syncthreads();
  __bf16* out = hnT + (size_t)b * NS * CC;
#pragma unroll
  for (int i = 0; i < 4; i++) {
    int n = n0 + ty + i * 8;
    out[(size_t)n * CC + c0 + tx] = (__bf16)tile[tx][ty + i * 8];
  }
}

// fp32 -> bf16 weight conversion for the four 512x512 weights.
__global__ __launch_bounds__(256) void cvt_w(const float* __restrict__ w0, const float* __restrict__ w1,
                                             const float* __restrict__ w2, const float* __restrict__ w3,
                                             __bf16* __restrict__ o0, __bf16* __restrict__ o1,
                                             __bf16* __restrict__ o2, __bf16* __restrict__ o3) {
  int tsel = blockIdx.x >> 8;
  int i = (blockIdx.x & 255) * 256 + threadIdx.x;
  const float* src = tsel == 0 ? w0 : tsel == 1 ? w1 : tsel == 2 ? w2 : w3;
  __bf16* dst = tsel == 0 ? o0 : tsel == 1 ? o1 : tsel == 2 ? o2 : o3;
  float4 v = ((const float4*)src)[i];
  bf16_4 r;
  r[0] = (__bf16)v.x; r[1] = (__bf16)v.y; r[2] = (__bf16)v.z; r[3] = (__bf16)v.w;
  ((bf16_4*)dst)[i] = r;
}

// ---------------- Shared GEMM core (512 threads, 8 waves, BK=128) ----------------
// 128x128 block tile: acc[m,n] += sum_k A[m,k]*B[n,k]; A/B pre-offset to tile
// origin. Wave w owns 64x32: wrow=(w>>2)*64, wcol=(w&3)*32 -> acc 4x2 f32_4 =
// 32 AGPRs. BK=128 quarters the 2-barrier stall events vs BK=32 (the dominant
// measured cost: each iteration pays a full vmcnt(0) drain at the barrier) and
// puts 32 MFMA/wave behind each drain. K=128 tile = FOUR stacked [128][32]
// bf16 planes (8 KB each), so the proven zero-conflict staging/read swizzles
// apply unchanged per plane. LDS 64 KB; occupancy stays 2 blocks/CU (we are
// register-limited there already — m132's BK=128 occupancy cliff doesn't apply).
__device__ __forceinline__ void gemm_core(const __bf16* __restrict__ A, const __bf16* __restrict__ B,
                                          int K, int lda, int ldb,
                                          __bf16* lA, __bf16* lB, f32_4 (&acc)[4][2]) {
  const int t = threadIdx.x;
  const int lane = t & 63;
  const int wave = t >> 6;
  const int lrow = lane & 15, quad = lane >> 4;
  const int wrow = (wave >> 2) * 64, wcol = (wave & 3) * 32;
  const int co = (quad ^ ((lrow >> 1) & 3)) * 8;   // swizzled read chunk
  const int r0 = t >> 2;                            // 0..127: staged row
  const int kp = ((t & 3) ^ ((t >> 3) & 3)) * 8;   // swizzled staged global chunk
  const __bf16* pA = A + (size_t)r0 * lda + kp;
  const __bf16* pB = B + (size_t)r0 * ldb + kp;
  for (int k0 = 0; k0 < K; k0 += 128) {
    __syncthreads();
#pragma unroll
    for (int pl = 0; pl < 4; pl++) {
      gld_lds16(pA + k0 + pl * 32, &lA[pl * 4096 + t * 8]);
      gld_lds16(pB + k0 + pl * 32, &lB[pl * 4096 + t * 8]);
    }
    __syncthreads();
#pragma unroll
    for (int ks = 0; ks < 4; ks++) {
      const __bf16* la = lA + ks * 4096;
      const __bf16* lb = lB + ks * 4096;
      bf16_8 af[4], bfr[2];
#pragma unroll
      for (int i = 0; i < 4; i++)
        af[i] = *(const bf16_8*)&la[(wrow + i * 16 + lrow) * 32 + co];
#pragma unroll
      for (int j = 0; j < 2; j++)
        bfr[j] = *(const bf16_8*)&lb[(wcol + j * 16 + lrow) * 32 + co];
#pragma unroll
      for (int i = 0; i < 4; i++)
#pragma unroll
        for (int j = 0; j < 2; j++)
          acc[i][j] = __builtin_amdgcn_mfma_f32_16x16x32_bf16(af[i], bfr[j], acc[i][j], 0, 0, 0);
    }
  }
}

// ---- Coalesced epilogue: stage acc into padded LDS, drain row-linear. ----
// lsr UNIONS with the dead lA/lB staging space (used only after the K-loop).
__device__ __forceinline__ void stage_acc(float* ls, const f32_4 (&acc)[4][2], int pass) {
  const int t = threadIdx.x;
  const int lane = t & 63, wave = t >> 6;
  const int lrow = lane & 15, quad = lane >> 4;
  const int wrow = (wave >> 2) * 64, wcol = (wave & 3) * 32;
  if ((wrow >> 6) == pass) {
#pragma unroll
    for (int i = 0; i < 4; i++)
#pragma unroll
      for (int r = 0; r < 4; r++)
#pragma unroll
        for (int jj = 0; jj < 2; jj++)
          ls[(i * 16 + quad * 4 + r) * RSTRIDE + wcol + jj * 16 + lrow] = acc[i][jj][r];
  }
}

__device__ __forceinline__ void drain_bf16(const float* ls, __bf16* gdst, int ldg) {
  const int t = threadIdx.x;
#pragma unroll
  for (int k2 = 0; k2 < 4; k2++) {
    int idx = k2 * 512 + t;
    int row = idx >> 5, col = (idx & 31) * 4;
    f32_4 v = *(const f32_4*)&ls[row * RSTRIDE + col];
    bf16_4 o;
    o[0] = (__bf16)v[0]; o[1] = (__bf16)v[1]; o[2] = (__bf16)v[2]; o[3] = (__bf16)v[3];
    *(bf16_4*)&gdst[(size_t)row * ldg + col] = o;
  }
}

// ---------------- Fused Q/K/V projections (one dispatch, 768 blocks) ----------
__global__ __launch_bounds__(512, 4) void qkv_gemm(const __bf16* __restrict__ hnT,
                                                   const __bf16* __restrict__ Wq,
                                                   const __bf16* __restrict__ Wk,
                                                   const __bf16* __restrict__ Wv,
                                                   const float* __restrict__ bq,
                                                   const float* __restrict__ bk,
                                                   const float* __restrict__ bv,
                                                   __bf16* __restrict__ qT,
                                                   __bf16* __restrict__ kT,
                                                   __bf16* __restrict__ vv) {
  __shared__ char smem[SMEM_BYTES];
  __bf16* lA = (__bf16*)smem;
  __bf16* lB = (__bf16*)(smem + 32768);
  float* lsr = (float*)smem;
  const int b = blockIdx.z;
  const int id = blockIdx.x;
  const int sel = id >> 7;
  const int r = id & 127;
  const long long sBNC = (long long)NS * CC;
  const long long sBCN = (long long)CC * NS;

  int m0, n0, N;
  const __bf16 *Ap, *Bp;
  __bf16* Cp;
  const float* bias;
  if (sel < 2) {  // q/k: out[n, o] = sum_c hnT[n,c] W[o,c] + b[o]
    m0 = (r >> 2) * TILE;
    n0 = (r & 3) * TILE;
    Ap = hnT + (size_t)b * sBNC + (size_t)m0 * CC;
    Bp = (sel == 0 ? Wq : Wk) + (size_t)n0 * CC;
    Cp = (sel == 0 ? qT : kT) + (size_t)b * sBNC;
    bias = (sel == 0 ? bq : bk);
    N = CC;
  } else {  // v: out[o, n] = sum_c Wv[o,c] hnT[n,c] + bv[o]
    m0 = (r & 3) * TILE;
    n0 = (r >> 2) * TILE;
    Ap = Wv + (size_t)m0 * CC;
    Bp = hnT + (size_t)b * sBNC + (size_t)n0 * CC;
    Cp = vv + (size_t)b * sBCN;
    bias = bv;
    N = NS;
  }

  f32_4 acc[4][2];
#pragma unroll
  for (int i = 0; i < 4; i++)
#pragma unroll
    for (int j = 0; j < 2; j++) acc[i][j] = {0.f, 0.f, 0.f, 0.f};

  gemm_core(Ap, Bp, CC, CC, CC, lA, lB, acc);

  // Fold bias into acc.
  const int t = threadIdx.x;
  const int lane = t & 63;
  const int lrow = lane & 15, quad = lane >> 4;
  const int wave = t >> 6;
  const int wrow = (wave >> 2) * 64, wcol = (wave & 3) * 32;
#pragma unroll
  for (int i = 0; i < 4; i++)
#pragma unroll
    for (int r2 = 0; r2 < 4; r2++) {
      float rowb = (sel == 2) ? bias[m0 + wrow + i * 16 + quad * 4 + r2] : 0.f;
#pragma unroll
      for (int j = 0; j < 2; j++) {
        float cb = (sel < 2) ? bias[n0 + wcol + j * 16 + lrow] : rowb;
        acc[i][j][r2] += cb;
      }
    }

#pragma unroll
  for (int p = 0; p < 2; p++) {
    __syncthreads();
    stage_acc(lsr, acc, p);
    __syncthreads();
    drain_bf16(lsr, Cp + (size_t)(m0 + p * 64) * N + n0, N);
  }
}

// ---------------- S-GEMM with fused exp + row-sum accumulation ---------------
// E[i,j] = exp(scale * sum_c qT[i,c] kT[j,c])  (bf16, unnormalized);
// l[i] += row sums (fp32 atomics). Division by l later = exact softmax.
// Epilogue: direct scattered stores (measured faster than LDS repack here).
// XCD swizzle: xcd j = g&7 owns (b, m-octet); 8x8 supertiles inside.
__global__ __launch_bounds__(512, 4) void e_gemm(const __bf16* __restrict__ qT,
                                                 const __bf16* __restrict__ kT,
                                                 __bf16* __restrict__ E,
                                                 float* __restrict__ l,
                                                 float scale) {
  __shared__ char smem[SMEM_BYTES];
  __bf16* lA = (__bf16*)smem;
  __bf16* lB = (__bf16*)(smem + 32768);
  const int g = blockIdx.x;
  const int j = g & 7;
  const int b = j & 1;
  const int moct = j >> 1;        // 0..3
  const int k = g >> 3;           // 0..255
  const int sc = k >> 6;          // n-supercolumn 0..3
  const int rem = k & 63;
  const int m0 = (moct * 8 + (rem >> 3)) * TILE;
  const int n0 = (sc * 8 + (rem & 7)) * TILE;
  const long long sBNC = (long long)NS * CC;
  const long long sBNN = (long long)NS * NS;
  const __bf16* Ap = qT + (size_t)b * sBNC + (size_t)m0 * CC;
  const __bf16* Bp = kT + (size_t)b * sBNC + (size_t)n0 * CC;

  f32_4 acc[4][2];
#pragma unroll
  for (int i = 0; i < 4; i++)
#pragma unroll
    for (int jj = 0; jj < 2; jj++) acc[i][jj] = {0.f, 0.f, 0.f, 0.f};

  gemm_core(Ap, Bp, CC, CC, CC, lA, lB, acc);

  const int t = threadIdx.x;
  const int lane = t & 63;
  const int lrow = lane & 15, quad = lane >> 4;
  const int wave = t >> 6;
  const int wrow = (wave >> 2) * 64, wcol = (wave & 3) * 32;
  __bf16* Ep = E + (size_t)b * sBNN;
  float* lp = l + (size_t)b * NS;
#pragma unroll
  for (int i = 0; i < 4; i++) {
#pragma unroll
    for (int r = 0; r < 4; r++) {
      int gm = m0 + wrow + i * 16 + quad * 4 + r;
      float rp = 0.f;
#pragma unroll
      for (int jj = 0; jj < 2; jj++) {
        int gn = n0 + wcol + jj * 16 + lrow;
        float ev = __expf(acc[i][jj][r] * scale);
        rp += ev;
        Ep[(size_t)gm * NS + gn] = (__bf16)ev;
      }
      rp += __shfl_down(rp, 8, 16);
      rp += __shfl_down(rp, 4, 16);
      rp += __shfl_down(rp, 2, 16);
      rp += __shfl_down(rp, 1, 16);
      if (lrow == 0) atomicAdd(&lp[gm], rp);
    }
  }
}

// ---------------- attn*V split-K=4 GEMM (1024 blocks, XCD-swizzled) ----------
__global__ __launch_bounds__(512, 4) void ao_split4(const __bf16* __restrict__ E,
                                                    const __bf16* __restrict__ vv,
                                                    __bf16* __restrict__ p0,
                                                    __bf16* __restrict__ p1,
                                                    __bf16* __restrict__ p2,
                                                    __bf16* __restrict__ p3) {
  __shared__ char smem[SMEM_BYTES];
  __bf16* lA = (__bf16*)smem;
  __bf16* lB = (__bf16*)(smem + 32768);
  float* lsr = (float*)smem;
  const int g = blockIdx.x;
  const int j = g & 7;
  const int b = j & 1;
  const int split = j >> 1;
  const int k = g >> 3;            // 0..127
  const int m0 = (k >> 2) * TILE;  // over NS (i), 32 tiles
  const int n0 = (k & 3) * TILE;   // over CC (c), 4 tiles
  const long long sBNN = (long long)NS * NS;
  const long long sBCN = (long long)CC * NS;
  const long long sBNC = (long long)NS * CC;
  const __bf16* Ap = E + (size_t)b * sBNN + (size_t)m0 * NS + (size_t)split * 1024;
  const __bf16* Bp = vv + (size_t)b * sBCN + (size_t)n0 * NS + (size_t)split * 1024;
  __bf16* Cp = (split == 0 ? p0 : split == 1 ? p1 : split == 2 ? p2 : p3) + (size_t)b * sBNC;

  f32_4 acc[4][2];
#pragma unroll
  for (int i = 0; i < 4; i++)
#pragma unroll
    for (int jj = 0; jj < 2; jj++) acc[i][jj] = {0.f, 0.f, 0.f, 0.f};

  gemm_core(Ap, Bp, 1024, NS, NS, lA, lB, acc);

#pragma unroll
  for (int p = 0; p < 2; p++) {
    __syncthreads();
    stage_acc(lsr, acc, p);
    __syncthreads();
    drain_bf16(lsr, Cp + (size_t)(m0 + p * 64) * CC + n0, CC);
  }
}

// (p0+p1+p2+p3)/l[row] -> aoT (bf16). p3 may alias the output (elementwise RAW).
__global__ __launch_bounds__(256) void reduce_ao4(const __bf16* __restrict__ p0,
                                                  const __bf16* __restrict__ p1,
                                                  const __bf16* __restrict__ p2,
                                                  const __bf16* __restrict__ p3,
                                                  const float* __restrict__ l,
                                                  __bf16* __restrict__ o) {
  int i = blockIdx.x * 256 + threadIdx.x;   // bf16_8 units, [B][NS][CC]
  int row = i >> 6;                          // 64 vecs per row of 512 chans
  float inv = 1.f / l[row];
  bf16_8 a = ((const bf16_8*)p0)[i];
  bf16_8 c = ((const bf16_8*)p1)[i];
  bf16_8 d = ((const bf16_8*)p2)[i];
  bf16_8 e = ((const bf16_8*)p3)[i];
  bf16_8 r;
#pragma unroll
  for (int k = 0; k < 8; k++)
    r[k] = (__bf16)(((float)a[k] + (float)c[k] + (float)d[k] + (float)e[k]) * inv);
  ((bf16_8*)o)[i] = r;
}

// ---------------- Output projection, split-K=2, bf16 partials ----------------
// Partials in bf16: halves wo's store traffic and final_out's read traffic;
// |partial| ~ O(1) and the absmax budget has 3x headroom.
__global__ __launch_bounds__(512, 4) void wo_split(const __bf16* __restrict__ Wo,
                                                   const __bf16* __restrict__ aoT,
                                                   __bf16* __restrict__ pw0,
                                                   __bf16* __restrict__ pw1) {
  __shared__ char smem[SMEM_BYTES];
  __bf16* lA = (__bf16*)smem;
  __bf16* lB = (__bf16*)(smem + 32768);
  float* lsr = (float*)smem;
  const int b = blockIdx.z & 1;
  const int split = blockIdx.z >> 1;
  const int m0 = blockIdx.y * TILE;   // over CC (o)
  const int n0 = blockIdx.x * TILE;   // over NS (n)
  const long long sBNC = (long long)NS * CC;
  const long long sBCN = (long long)CC * NS;
  const __bf16* Ap = Wo + (size_t)m0 * CC + (size_t)split * 256;
  const __bf16* Bp = aoT + (size_t)b * sBNC + (size_t)n0 * CC + (size_t)split * 256;
  __bf16* Cp = (split ? pw1 : pw0) + (size_t)b * sBCN;

  f32_4 acc[4][2];
#pragma unroll
  for (int i = 0; i < 4; i++)
#pragma unroll
    for (int j = 0; j < 2; j++) acc[i][j] = {0.f, 0.f, 0.f, 0.f};

  gemm_core(Ap, Bp, 256, CC, CC, lA, lB, acc);

#pragma unroll
  for (int p = 0; p < 2; p++) {
    __syncthreads();
    stage_acc(lsr, acc, p);
    __syncthreads();
    drain_bf16(lsr, Cp + (size_t)(m0 + p * 64) * NS + n0, NS);
  }
}

// out = pw0 + pw1 + bo[o] + x   (bf16 partials, fp32 out, vectorized)
__global__ __launch_bounds__(256) void final_out(const __bf16* __restrict__ pw0,
                                                 const __bf16* __restrict__ pw1,
                                                 const float* __restrict__ bo,
                                                 const float* __restrict__ x,
                                                 float* __restrict__ out) {
  int i = blockIdx.x * 256 + threadIdx.x;   // 4-elem units over [B][CC][NS]
  int o = (i >> 10) & (CC - 1);             // 1024 units per channel-row
  float bias = bo[o];
  bf16_4 a = ((const bf16_4*)pw0)[i];
  bf16_4 c = ((const bf16_4*)pw1)[i];
  float4 xr = ((const float4*)x)[i];
  float4 r;
  r.x = (float)a[0] + (float)c[0] + bias + xr.x;
  r.y = (float)a[1] + (float)c[1] + bias + xr.y;
  r.z = (float)a[2] + (float)c[2] + bias + xr.z;
  r.w = (float)a[3] + (float)c[3] + bias + xr.w;
  ((float4*)out)[i] = r;
}

extern "C" void kernel_launch(void* const* d_in, const int* in_sizes, int n_in,
                              void* d_out, int out_size, void* d_ws, size_t ws_size,
                              hipStream_t stream) {
  const float* x = (const float*)d_in[0];
  const float* gamma = (const float*)d_in[1];
  const float* beta = (const float*)d_in[2];
  const float* Wq = (const float*)d_in[3];
  const float* bq = (const float*)d_in[4];
  const float* Wk = (const float*)d_in[5];
  const float* bk = (const float*)d_in[6];
  const float* Wv = (const float*)d_in[7];
  const float* bv = (const float*)d_in[8];
  const float* Wo = (const float*)d_in[9];
  const float* bo = (const float*)d_in[10];
  float* out = (float*)d_out;

  char* ws = (char*)d_ws;
  __bf16* hnT = (__bf16*)(ws + 0);           // [B][NS][CC] 8 MiB; later ao partial p0
  __bf16* qT  = (__bf16*)(ws + 8388608);     // later p1
  __bf16* kT  = (__bf16*)(ws + 16777216);    // later p2
  __bf16* vv  = (__bf16*)(ws + 25165824);    // [B][CC][NS]
  __bf16* aoT = (__bf16*)(ws + 33554432);    // [B][NS][CC]; doubles as p3 (RAW-safe)
  __bf16* Eb  = (__bf16*)(ws + 41943040);    // [B][NS][NS] 64 MiB; later wo partials
  __bf16* pw0 = (__bf16*)(ws + 41943040);    // 8 MiB (inside dead E region)
  __bf16* pw1 = (__bf16*)(ws + 50331648);    // 8 MiB
  __bf16* Wqb = (__bf16*)(ws + 109051904);   // dead after qkv -> reused as lsum
  __bf16* Wkb = (__bf16*)(ws + 109576192);
  __bf16* Wvb = (__bf16*)(ws + 110100480);
  __bf16* Wob = (__bf16*)(ws + 110624768);
  float* stats = (float*)(ws + 111149056);
  float* lsum = (float*)(ws + 109051904);    // [B][NS] fp32, aliases dead Wqb
  __bf16* p0 = hnT;
  __bf16* p1 = qT;
  __bf16* p2 = kT;
  __bf16* p3 = aoT;

  const float scale = 0.044194173824159216f;  // 512^-0.5

  cvt_w<<<1024, 256, 0, stream>>>(Wq, Wk, Wv, Wo, Wqb, Wkb, Wvb, Wob);
  gn_stats<<<BB * NGROUP, 256, 0, stream>>>(x, stats);
  gn_apply_t<<<dim3(NS / 32, CC / 32, BB), dim3(32, 8), 0, stream>>>(x, stats, gamma, beta, hnT);

  // Fused Q/K/V projections: 768 blocks.
  qkv_gemm<<<dim3(384, 1, BB), 512, 0, stream>>>(hnT, Wqb, Wkb, Wvb, bq, bk, bv, qT, kT, vv);

  // Zero row-sum accumulator (Wqb is dead now), then E-GEMM with fused exp+rowsum.
  hipMemsetAsync(lsum, 0, BB * NS * sizeof(float), stream);
  e_gemm<<<2048, 512, 0, stream>>>(qT, kT, Eb, lsum, scale);

  // aoT partials = E * v^T over quarter-K splits (1024 blocks, XCD-swizzled).
  ao_split4<<<1024, 512, 0, stream>>>(Eb, vv, p0, p1, p2, p3);
  reduce_ao4<<<2048, 256, 0, stream>>>(p0, p1, p2, p3, lsum, aoT);

  // Output projection split-K=2 (512 blocks, bf16 partials) + fused epilogue.
  wo_split<<<dim3(NS / TILE, CC / TILE, 2 * BB), 512, 0, stream>>>(Wob, aoT, pw0, pw1);
  final_out<<<4096, 256, 0, stream>>>(pw0, pw1, bo, x, out);
}

// Round 9
// 264.573 us; speedup vs baseline: 1.0240x; 1.0240x over previous
//
#include <hip/hip_runtime.h>

// Problem constants: x [B=2, C=512, H=64, W=64], 32 groups, N = H*W = 4096.
#define BB 2
#define CC 512
#define NS 4096
#define NGROUP 32
#define TILE 128
#define RSTRIDE 132   // repack LDS row stride (floats): 128 + 4 pad

typedef __bf16 bf16_8 __attribute__((ext_vector_type(8)));
typedef __bf16 bf16_4 __attribute__((ext_vector_type(4)));
typedef float f32_4 __attribute__((ext_vector_type(4)));

#define SMEM_BYTES 33792   // max(32KB BK=64 A+B staging, 64*132*4 repack)

__device__ __forceinline__ void gld_lds16(const __bf16* g, __bf16* l) {
  __builtin_amdgcn_global_load_lds(
      (const __attribute__((address_space(1))) unsigned int*)g,
      (__attribute__((address_space(3))) unsigned int*)l, 16, 0, 0);
}

// ---------------- GroupNorm ----------------
__global__ __launch_bounds__(256) void gn_stats(const float* __restrict__ x,
                                                float* __restrict__ stats) {
  const float4* p = (const float4*)(x + (size_t)blockIdx.x * 65536);
  float s = 0.f, q = 0.f;
  for (int i = threadIdx.x; i < 16384; i += 256) {
    float4 v = p[i];
    s += v.x + v.y + v.z + v.w;
    q += v.x * v.x + v.y * v.y + v.z * v.z + v.w * v.w;
  }
#pragma unroll
  for (int off = 32; off > 0; off >>= 1) {
    s += __shfl_down(s, off, 64);
    q += __shfl_down(q, off, 64);
  }
  __shared__ float ls[4], lq[4];
  int wave = threadIdx.x >> 6, lane = threadIdx.x & 63;
  if (lane == 0) { ls[wave] = s; lq[wave] = q; }
  __syncthreads();
  if (threadIdx.x == 0) {
    float S = ls[0] + ls[1] + ls[2] + ls[3];
    float Q = lq[0] + lq[1] + lq[2] + lq[3];
    float mean = S * (1.f / 65536.f);
    float var = Q * (1.f / 65536.f) - mean * mean;
    stats[blockIdx.x * 2] = mean;
    stats[blockIdx.x * 2 + 1] = rsqrtf(var + 1e-6f);
  }
}

// Normalize + transpose: x[b][c][n] (fp32) -> hnT[b][n][c] (bf16), 32x32 tiles via LDS.
__global__ __launch_bounds__(256) void gn_apply_t(const float* __restrict__ x,
                                                  const float* __restrict__ stats,
                                                  const float* __restrict__ gamma,
                                                  const float* __restrict__ beta,
                                                  __bf16* __restrict__ hnT) {
  __shared__ float tile[32][33];
  int b = blockIdx.z;
  int c0 = blockIdx.y * 32;
  int n0 = blockIdx.x * 32;
  int tx = threadIdx.x;  // 0..31
  int ty = threadIdx.y;  // 0..7
  const float* xb = x + (size_t)b * CC * NS;
#pragma unroll
  for (int i = 0; i < 4; i++) {
    int c = c0 + ty + i * 8;
    float mean = stats[(b * NGROUP + (c >> 4)) * 2 + 0];
    float rstd = stats[(b * NGROUP + (c >> 4)) * 2 + 1];
    float v = xb[(size_t)c * NS + n0 + tx];
    tile[ty + i * 8][tx] = (v - mean) * rstd * gamma[c] + beta[c];
  }
  __syncthreads();
  __bf16* out = hnT + (size_t)b * NS * CC;
#pragma unroll
  for (int i = 0; i < 4; i++) {
    int n = n0 + ty + i * 8;
    out[(size_t)n * CC + c0 + tx] = (__bf16)tile[tx][ty + i * 8];
  }
}

// fp32 -> bf16 weight conversion for the four 512x512 weights.
__global__ __launch_bounds__(256) void cvt_w(const float* __restrict__ w0, const float* __restrict__ w1,
                                             const float* __restrict__ w2, const float* __restrict__ w3,
                                             __bf16* __restrict__ o0, __bf16* __restrict__ o1,
                                             __bf16* __restrict__ o2, __bf16* __restrict__ o3) {
  int tsel = blockIdx.x >> 8;
  int i = (blockIdx.x & 255) * 256 + threadIdx.x;
  const float* src = tsel == 0 ? w0 : tsel == 1 ? w1 : tsel == 2 ? w2 : w3;
  __bf16* dst = tsel == 0 ? o0 : tsel == 1 ? o1 : tsel == 2 ? o2 : o3;
  float4 v = ((const float4*)src)[i];
  bf16_4 r;
  r[0] = (__bf16)v.x; r[1] = (__bf16)v.y; r[2] = (__bf16)v.z; r[3] = (__bf16)v.w;
  ((bf16_4*)dst)[i] = r;
}

// ------------- Shared GEMM core (256 threads, 4 waves, 64x64/wave, BK=64) -------------
// 128x128 block tile: acc[m,n] += sum_k A[m,k]*B[n,k]; A/B pre-offset to tile
// origin. Wave w owns 64x64: wrow=(w>>1)*64, wcol=(w&1)*64 -> acc 4x4 f32_4 =
// 64 AGPRs. 64x64 wave tile = 16 MACs per LDS byte (vs 10.7 for 64x32) — the
// measured limiter is LDS read bandwidth, so maximize reuse per ds_read.
// BK=64 = two stacked [128][32] bf16 planes per operand; the proven
// zero-conflict XOR swizzles apply unchanged per plane. LDS 32 KB.
__device__ __forceinline__ void gemm_core(const __bf16* __restrict__ A, const __bf16* __restrict__ B,
                                          int K, int lda, int ldb,
                                          __bf16* lA, __bf16* lB, f32_4 (&acc)[4][4]) {
  const int t = threadIdx.x;
  const int lane = t & 63;
  const int wave = t >> 6;
  const int lrow = lane & 15, quad = lane >> 4;
  const int wrow = (wave >> 1) * 64, wcol = (wave & 1) * 64;
  const int co = (quad ^ ((lrow >> 1) & 3)) * 8;   // swizzled read chunk
  const int r0 = t >> 2;                            // 0..63: staged row (lower half)
  const int kp = ((t & 3) ^ ((t >> 3) & 3)) * 8;   // swizzled staged global chunk
  const __bf16* pA0 = A + (size_t)r0 * lda + kp;
  const __bf16* pA1 = A + (size_t)(r0 + 64) * lda + kp;
  const __bf16* pB0 = B + (size_t)r0 * ldb + kp;
  const __bf16* pB1 = B + (size_t)(r0 + 64) * ldb + kp;
  for (int k0 = 0; k0 < K; k0 += 64) {
    __syncthreads();
    // plane 0 (k0..k0+32), plane 1 (k0+32..k0+64); each plane [128][32] = 4096 elems
    gld_lds16(pA0 + k0,      &lA[t * 8]);
    gld_lds16(pA1 + k0,      &lA[2048 + t * 8]);
    gld_lds16(pA0 + k0 + 32, &lA[4096 + t * 8]);
    gld_lds16(pA1 + k0 + 32, &lA[6144 + t * 8]);
    gld_lds16(pB0 + k0,      &lB[t * 8]);
    gld_lds16(pB1 + k0,      &lB[2048 + t * 8]);
    gld_lds16(pB0 + k0 + 32, &lB[4096 + t * 8]);
    gld_lds16(pB1 + k0 + 32, &lB[6144 + t * 8]);
    __syncthreads();
#pragma unroll
    for (int ks = 0; ks < 2; ks++) {
      const __bf16* la = lA + ks * 4096;
      const __bf16* lb = lB + ks * 4096;
      bf16_8 af[4], bfr[4];
#pragma unroll
      for (int i = 0; i < 4; i++)
        af[i] = *(const bf16_8*)&la[(wrow + i * 16 + lrow) * 32 + co];
#pragma unroll
      for (int j = 0; j < 4; j++)
        bfr[j] = *(const bf16_8*)&lb[(wcol + j * 16 + lrow) * 32 + co];
#pragma unroll
      for (int i = 0; i < 4; i++)
#pragma unroll
        for (int j = 0; j < 4; j++)
          acc[i][j] = __builtin_amdgcn_mfma_f32_16x16x32_bf16(af[i], bfr[j], acc[i][j], 0, 0, 0);
    }
  }
}

// ---- Coalesced epilogue: stage acc into padded LDS, drain row-linear. ----
// lsr UNIONS with the dead lA/lB staging space (used only after the K-loop).
__device__ __forceinline__ void stage_acc(float* ls, const f32_4 (&acc)[4][4], int pass) {
  const int t = threadIdx.x;
  const int lane = t & 63, wave = t >> 6;
  const int lrow = lane & 15, quad = lane >> 4;
  const int wrow = (wave >> 1) * 64, wcol = (wave & 1) * 64;
  if ((wrow >> 6) == pass) {
#pragma unroll
    for (int i = 0; i < 4; i++)
#pragma unroll
      for (int r = 0; r < 4; r++)
#pragma unroll
        for (int jj = 0; jj < 4; jj++)
          ls[(i * 16 + quad * 4 + r) * RSTRIDE + wcol + jj * 16 + lrow] = acc[i][jj][r];
  }
}

__device__ __forceinline__ void drain_bf16(const float* ls, __bf16* gdst, int ldg) {
  const int t = threadIdx.x;
#pragma unroll
  for (int k2 = 0; k2 < 8; k2++) {
    int idx = k2 * 256 + t;
    int row = idx >> 5, col = (idx & 31) * 4;
    f32_4 v = *(const f32_4*)&ls[row * RSTRIDE + col];
    bf16_4 o;
    o[0] = (__bf16)v[0]; o[1] = (__bf16)v[1]; o[2] = (__bf16)v[2]; o[3] = (__bf16)v[3];
    *(bf16_4*)&gdst[(size_t)row * ldg + col] = o;
  }
}

// ---------------- Fused Q/K/V projections (one dispatch, 768 blocks) ----------
__global__ __launch_bounds__(256) void qkv_gemm(const __bf16* __restrict__ hnT,
                                                const __bf16* __restrict__ Wq,
                                                const __bf16* __restrict__ Wk,
                                                const __bf16* __restrict__ Wv,
                                                const float* __restrict__ bq,
                                                const float* __restrict__ bk,
                                                const float* __restrict__ bv,
                                                __bf16* __restrict__ qT,
                                                __bf16* __restrict__ kT,
                                                __bf16* __restrict__ vv) {
  __shared__ char smem[SMEM_BYTES];
  __bf16* lA = (__bf16*)smem;
  __bf16* lB = (__bf16*)(smem + 16384);
  float* lsr = (float*)smem;
  const int b = blockIdx.z;
  const int id = blockIdx.x;
  const int sel = id >> 7;
  const int r = id & 127;
  const long long sBNC = (long long)NS * CC;
  const long long sBCN = (long long)CC * NS;

  int m0, n0, N;
  const __bf16 *Ap, *Bp;
  __bf16* Cp;
  const float* bias;
  if (sel < 2) {  // q/k: out[n, o] = sum_c hnT[n,c] W[o,c] + b[o]
    m0 = (r >> 2) * TILE;
    n0 = (r & 3) * TILE;
    Ap = hnT + (size_t)b * sBNC + (size_t)m0 * CC;
    Bp = (sel == 0 ? Wq : Wk) + (size_t)n0 * CC;
    Cp = (sel == 0 ? qT : kT) + (size_t)b * sBNC;
    bias = (sel == 0 ? bq : bk);
    N = CC;
  } else {  // v: out[o, n] = sum_c Wv[o,c] hnT[n,c] + bv[o]
    m0 = (r & 3) * TILE;
    n0 = (r >> 2) * TILE;
    Ap = Wv + (size_t)m0 * CC;
    Bp = hnT + (size_t)b * sBNC + (size_t)n0 * CC;
    Cp = vv + (size_t)b * sBCN;
    bias = bv;
    N = NS;
  }

  f32_4 acc[4][4];
#pragma unroll
  for (int i = 0; i < 4; i++)
#pragma unroll
    for (int j = 0; j < 4; j++) acc[i][j] = {0.f, 0.f, 0.f, 0.f};

  gemm_core(Ap, Bp, CC, CC, CC, lA, lB, acc);

  // Fold bias into acc.
  const int t = threadIdx.x;
  const int lane = t & 63;
  const int lrow = lane & 15, quad = lane >> 4;
  const int wave = t >> 6;
  const int wrow = (wave >> 1) * 64, wcol = (wave & 1) * 64;
#pragma unroll
  for (int i = 0; i < 4; i++)
#pragma unroll
    for (int r2 = 0; r2 < 4; r2++) {
      float rowb = (sel == 2) ? bias[m0 + wrow + i * 16 + quad * 4 + r2] : 0.f;
#pragma unroll
      for (int j = 0; j < 4; j++) {
        float cb = (sel < 2) ? bias[n0 + wcol + j * 16 + lrow] : rowb;
        acc[i][j][r2] += cb;
      }
    }

#pragma unroll
  for (int p = 0; p < 2; p++) {
    __syncthreads();
    stage_acc(lsr, acc, p);
    __syncthreads();
    drain_bf16(lsr, Cp + (size_t)(m0 + p * 64) * N + n0, N);
  }
}

// ---------------- S-GEMM with fused exp + row-sum accumulation ---------------
// E[i,j] = exp(scale * sum_c qT[i,c] kT[j,c])  (bf16, unnormalized);
// l[i] += row sums (fp32 atomics). Division by l later = exact softmax.
// Epilogue: direct scattered stores (measured faster than LDS repack here).
// XCD swizzle: xcd j = g&7 owns (b, m-octet); 8x8 supertiles inside.
__global__ __launch_bounds__(256) void e_gemm(const __bf16* __restrict__ qT,
                                              const __bf16* __restrict__ kT,
                                              __bf16* __restrict__ E,
                                              float* __restrict__ l,
                                              float scale) {
  __shared__ char smem[32768];
  __bf16* lA = (__bf16*)smem;
  __bf16* lB = (__bf16*)(smem + 16384);
  const int g = blockIdx.x;
  const int j = g & 7;
  const int b = j & 1;
  const int moct = j >> 1;        // 0..3
  const int k = g >> 3;           // 0..255
  const int sc = k >> 6;          // n-supercolumn 0..3
  const int rem = k & 63;
  const int m0 = (moct * 8 + (rem >> 3)) * TILE;
  const int n0 = (sc * 8 + (rem & 7)) * TILE;
  const long long sBNC = (long long)NS * CC;
  const long long sBNN = (long long)NS * NS;
  const __bf16* Ap = qT + (size_t)b * sBNC + (size_t)m0 * CC;
  const __bf16* Bp = kT + (size_t)b * sBNC + (size_t)n0 * CC;

  f32_4 acc[4][4];
#pragma unroll
  for (int i = 0; i < 4; i++)
#pragma unroll
    for (int jj = 0; jj < 4; jj++) acc[i][jj] = {0.f, 0.f, 0.f, 0.f};

  gemm_core(Ap, Bp, CC, CC, CC, lA, lB, acc);

  const int t = threadIdx.x;
  const int lane = t & 63;
  const int lrow = lane & 15, quad = lane >> 4;
  const int wave = t >> 6;
  const int wrow = (wave >> 1) * 64, wcol = (wave & 1) * 64;
  __bf16* Ep = E + (size_t)b * sBNN;
  float* lp = l + (size_t)b * NS;
#pragma unroll
  for (int i = 0; i < 4; i++) {
#pragma unroll
    for (int r = 0; r < 4; r++) {
      int gm = m0 + wrow + i * 16 + quad * 4 + r;
      float rp = 0.f;
#pragma unroll
      for (int jj = 0; jj < 4; jj++) {
        int gn = n0 + wcol + jj * 16 + lrow;
        float ev = __expf(acc[i][jj][r] * scale);
        rp += ev;
        Ep[(size_t)gm * NS + gn] = (__bf16)ev;
      }
      rp += __shfl_down(rp, 8, 16);
      rp += __shfl_down(rp, 4, 16);
      rp += __shfl_down(rp, 2, 16);
      rp += __shfl_down(rp, 1, 16);
      if (lrow == 0) atomicAdd(&lp[gm], rp);
    }
  }
}

// ---------------- attn*V split-K=4 GEMM (1024 blocks, XCD-swizzled) ----------
__global__ __launch_bounds__(256) void ao_split4(const __bf16* __restrict__ E,
                                                 const __bf16* __restrict__ vv,
                                                 __bf16* __restrict__ p0,
                                                 __bf16* __restrict__ p1,
                                                 __bf16* __restrict__ p2,
                                                 __bf16* __restrict__ p3) {
  __shared__ char smem[SMEM_BYTES];
  __bf16* lA = (__bf16*)smem;
  __bf16* lB = (__bf16*)(smem + 16384);
  float* lsr = (float*)smem;
  const int g = blockIdx.x;
  const int j = g & 7;
  const int b = j & 1;
  const int split = j >> 1;
  const int k = g >> 3;            // 0..127
  const int m0 = (k >> 2) * TILE;  // over NS (i), 32 tiles
  const int n0 = (k & 3) * TILE;   // over CC (c), 4 tiles
  const long long sBNN = (long long)NS * NS;
  const long long sBCN = (long long)CC * NS;
  const long long sBNC = (long long)NS * CC;
  const __bf16* Ap = E + (size_t)b * sBNN + (size_t)m0 * NS + (size_t)split * 1024;
  const __bf16* Bp = vv + (size_t)b * sBCN + (size_t)n0 * NS + (size_t)split * 1024;
  __bf16* Cp = (split == 0 ? p0 : split == 1 ? p1 : split == 2 ? p2 : p3) + (size_t)b * sBNC;

  f32_4 acc[4][4];
#pragma unroll
  for (int i = 0; i < 4; i++)
#pragma unroll
    for (int jj = 0; jj < 4; jj++) acc[i][jj] = {0.f, 0.f, 0.f, 0.f};

  gemm_core(Ap, Bp, 1024, NS, NS, lA, lB, acc);

#pragma unroll
  for (int p = 0; p < 2; p++) {
    __syncthreads();
    stage_acc(lsr, acc, p);
    __syncthreads();
    drain_bf16(lsr, Cp + (size_t)(m0 + p * 64) * CC + n0, CC);
  }
}

// (p0+p1+p2+p3)/l[row] -> aoT (bf16). p3 may alias the output (elementwise RAW).
__global__ __launch_bounds__(256) void reduce_ao4(const __bf16* __restrict__ p0,
                                                  const __bf16* __restrict__ p1,
                                                  const __bf16* __restrict__ p2,
                                                  const __bf16* __restrict__ p3,
                                                  const float* __restrict__ l,
                                                  __bf16* __restrict__ o) {
  int i = blockIdx.x * 256 + threadIdx.x;   // bf16_8 units, [B][NS][CC]
  int row = i >> 6;                          // 64 vecs per row of 512 chans
  float inv = 1.f / l[row];
  bf16_8 a = ((const bf16_8*)p0)[i];
  bf16_8 c = ((const bf16_8*)p1)[i];
  bf16_8 d = ((const bf16_8*)p2)[i];
  bf16_8 e = ((const bf16_8*)p3)[i];
  bf16_8 r;
#pragma unroll
  for (int k = 0; k < 8; k++)
    r[k] = (__bf16)(((float)a[k] + (float)c[k] + (float)d[k] + (float)e[k]) * inv);
  ((bf16_8*)o)[i] = r;
}

// ---------------- Output projection, split-K=2, bf16 partials ----------------
__global__ __launch_bounds__(256) void wo_split(const __bf16* __restrict__ Wo,
                                               const __bf16* __restrict__ aoT,
                                               __bf16* __restrict__ pw0,
                                               __bf16* __restrict__ pw1) {
  __shared__ char smem[SMEM_BYTES];
  __bf16* lA = (__bf16*)smem;
  __bf16* lB = (__bf16*)(smem + 16384);
  float* lsr = (float*)smem;
  const int b = blockIdx.z & 1;
  const int split = blockIdx.z >> 1;
  const int m0 = blockIdx.y * TILE;   // over CC (o)
  const int n0 = blockIdx.x * TILE;   // over NS (n)
  const long long sBNC = (long long)NS * CC;
  const long long sBCN = (long long)CC * NS;
  const __bf16* Ap = Wo + (size_t)m0 * CC + (size_t)split * 256;
  const __bf16* Bp = aoT + (size_t)b * sBNC + (size_t)n0 * CC + (size_t)split * 256;
  __bf16* Cp = (split ? pw1 : pw0) + (size_t)b * sBCN;

  f32_4 acc[4][4];
#pragma unroll
  for (int i = 0; i < 4; i++)
#pragma unroll
    for (int j = 0; j < 4; j++) acc[i][j] = {0.f, 0.f, 0.f, 0.f};

  gemm_core(Ap, Bp, 256, CC, CC, lA, lB, acc);

#pragma unroll
  for (int p = 0; p < 2; p++) {
    __syncthreads();
    stage_acc(lsr, acc, p);
    __syncthreads();
    drain_bf16(lsr, Cp + (size_t)(m0 + p * 64) * NS + n0, NS);
  }
}

// out = pw0 + pw1 + bo[o] + x   (bf16 partials, fp32 out, vectorized)
__global__ __launch_bounds__(256) void final_out(const __bf16* __restrict__ pw0,
                                                 const __bf16* __restrict__ pw1,
                                                 const float* __restrict__ bo,
                                                 const float* __restrict__ x,
                                                 float* __restrict__ out) {
  int i = blockIdx.x * 256 + threadIdx.x;   // 4-elem units over [B][CC][NS]
  int o = (i >> 10) & (CC - 1);             // 1024 units per channel-row
  float bias = bo[o];
  bf16_4 a = ((const bf16_4*)pw0)[i];
  bf16_4 c = ((const bf16_4*)pw1)[i];
  float4 xr = ((const float4*)x)[i];
  float4 r;
  r.x = (float)a[0] + (float)c[0] + bias + xr.x;
  r.y = (float)a[1] + (float)c[1] + bias + xr.y;
  r.z = (float)a[2] + (float)c[2] + bias + xr.z;
  r.w = (float)a[3] + (float)c[3] + bias + xr.w;
  ((float4*)out)[i] = r;
}

extern "C" void kernel_launch(void* const* d_in, const int* in_sizes, int n_in,
                              void* d_out, int out_size, void* d_ws, size_t ws_size,
                              hipStream_t stream) {
  const float* x = (const float*)d_in[0];
  const float* gamma = (const float*)d_in[1];
  const float* beta = (const float*)d_in[2];
  const float* Wq = (const float*)d_in[3];
  const float* bq = (const float*)d_in[4];
  const float* Wk = (const float*)d_in[5];
  const float* bk = (const float*)d_in[6];
  const float* Wv = (const float*)d_in[7];
  const float* bv = (const float*)d_in[8];
  const float* Wo = (const float*)d_in[9];
  const float* bo = (const float*)d_in[10];
  float* out = (float*)d_out;

  char* ws = (char*)d_ws;
  __bf16* hnT = (__bf16*)(ws + 0);           // [B][NS][CC] 8 MiB; later ao partial p0
  __bf16* qT  = (__bf16*)(ws + 8388608);     // later p1
  __bf16* kT  = (__bf16*)(ws + 16777216);    // later p2
  __bf16* vv  = (__bf16*)(ws + 25165824);    // [B][CC][NS]
  __bf16* aoT = (__bf16*)(ws + 33554432);    // [B][NS][CC]; doubles as p3 (RAW-safe)
  __bf16* Eb  = (__bf16*)(ws + 41943040);    // [B][NS][NS] 64 MiB; later wo partials
  __bf16* pw0 = (__bf16*)(ws + 41943040);    // 8 MiB (inside dead E region)
  __bf16* pw1 = (__bf16*)(ws + 50331648);    // 8 MiB
  __bf16* Wqb = (__bf16*)(ws + 109051904);   // dead after qkv -> reused as lsum
  __bf16* Wkb = (__bf16*)(ws + 109576192);
  __bf16* Wvb = (__bf16*)(ws + 110100480);
  __bf16* Wob = (__bf16*)(ws + 110624768);
  float* stats = (float*)(ws + 111149056);
  float* lsum = (float*)(ws + 109051904);    // [B][NS] fp32, aliases dead Wqb
  __bf16* p0 = hnT;
  __bf16* p1 = qT;
  __bf16* p2 = kT;
  __bf16* p3 = aoT;

  const float scale = 0.044194173824159216f;  // 512^-0.5

  cvt_w<<<1024, 256, 0, stream>>>(Wq, Wk, Wv, Wo, Wqb, Wkb, Wvb, Wob);
  gn_stats<<<BB * NGROUP, 256, 0, stream>>>(x, stats);
  gn_apply_t<<<dim3(NS / 32, CC / 32, BB), dim3(32, 8), 0, stream>>>(x, stats, gamma, beta, hnT);

  // Fused Q/K/V projections: 768 blocks.
  qkv_gemm<<<dim3(384, 1, BB), 256, 0, stream>>>(hnT, Wqb, Wkb, Wvb, bq, bk, bv, qT, kT, vv);

  // Zero row-sum accumulator (Wqb is dead now), then E-GEMM with fused exp+rowsum.
  hipMemsetAsync(lsum, 0, BB * NS * sizeof(float), stream);
  e_gemm<<<2048, 256, 0, stream>>>(qT, kT, Eb, lsum, scale);

  // aoT partials = E * v^T over quarter-K splits (1024 blocks, XCD-swizzled).
  ao_split4<<<1024, 256, 0, stream>>>(Eb, vv, p0, p1, p2, p3);
  reduce_ao4<<<2048, 256, 0, stream>>>(p0, p1, p2, p3, lsum, aoT);

  // Output projection split-K=2 (512 blocks, bf16 partials) + fused epilogue.
  wo_split<<<dim3(NS / TILE, CC / TILE, 2 * BB), 256, 0, stream>>>(Wob, aoT, pw0, pw1);
  final_out<<<4096, 256, 0, stream>>>(pw0, pw1, bo, x, out);
}

// Round 10
// 258.273 us; speedup vs baseline: 1.0490x; 1.0244x over previous
//
#include <hip/hip_runtime.h>

// Problem constants: x [B=2, C=512, H=64, W=64], 32 groups, N = H*W = 4096.
#define BB 2
#define CC 512
#define NS 4096
#define NGROUP 32
#define TILE 128
#define RSTRIDE 132   // repack LDS row stride (floats): 128 + 4 pad

typedef __bf16 bf16_8 __attribute__((ext_vector_type(8)));
typedef __bf16 bf16_4 __attribute__((ext_vector_type(4)));
typedef float f32_4 __attribute__((ext_vector_type(4)));

#define SMEM_BYTES 33792   // max(32KB BK=64 A+B staging, 64*132*4 repack)

__device__ __forceinline__ void gld_lds16(const __bf16* g, __bf16* l) {
  __builtin_amdgcn_global_load_lds(
      (const __attribute__((address_space(1))) unsigned int*)g,
      (__attribute__((address_space(3))) unsigned int*)l, 16, 0, 0);
}

// ---------------- GroupNorm ----------------
__global__ __launch_bounds__(256) void gn_stats(const float* __restrict__ x,
                                                float* __restrict__ stats) {
  const float4* p = (const float4*)(x + (size_t)blockIdx.x * 65536);
  float s = 0.f, q = 0.f;
  for (int i = threadIdx.x; i < 16384; i += 256) {
    float4 v = p[i];
    s += v.x + v.y + v.z + v.w;
    q += v.x * v.x + v.y * v.y + v.z * v.z + v.w * v.w;
  }
#pragma unroll
  for (int off = 32; off > 0; off >>= 1) {
    s += __shfl_down(s, off, 64);
    q += __shfl_down(q, off, 64);
  }
  __shared__ float ls[4], lq[4];
  int wave = threadIdx.x >> 6, lane = threadIdx.x & 63;
  if (lane == 0) { ls[wave] = s; lq[wave] = q; }
  __syncthreads();
  if (threadIdx.x == 0) {
    float S = ls[0] + ls[1] + ls[2] + ls[3];
    float Q = lq[0] + lq[1] + lq[2] + lq[3];
    float mean = S * (1.f / 65536.f);
    float var = Q * (1.f / 65536.f) - mean * mean;
    stats[blockIdx.x * 2] = mean;
    stats[blockIdx.x * 2 + 1] = rsqrtf(var + 1e-6f);
  }
}

// Normalize + transpose: x[b][c][n] (fp32) -> hnT[b][n][c] (bf16), 32x32 tiles via LDS.
__global__ __launch_bounds__(256) void gn_apply_t(const float* __restrict__ x,
                                                  const float* __restrict__ stats,
                                                  const float* __restrict__ gamma,
                                                  const float* __restrict__ beta,
                                                  __bf16* __restrict__ hnT) {
  __shared__ float tile[32][33];
  int b = blockIdx.z;
  int c0 = blockIdx.y * 32;
  int n0 = blockIdx.x * 32;
  int tx = threadIdx.x;  // 0..31
  int ty = threadIdx.y;  // 0..7
  const float* xb = x + (size_t)b * CC * NS;
#pragma unroll
  for (int i = 0; i < 4; i++) {
    int c = c0 + ty + i * 8;
    float mean = stats[(b * NGROUP + (c >> 4)) * 2 + 0];
    float rstd = stats[(b * NGROUP + (c >> 4)) * 2 + 1];
    float v = xb[(size_t)c * NS + n0 + tx];
    tile[ty + i * 8][tx] = (v - mean) * rstd * gamma[c] + beta[c];
  }
  __syncthreads();
  __bf16* out = hnT + (size_t)b * NS * CC;
#pragma unroll
  for (int i = 0; i < 4; i++) {
    int n = n0 + ty + i * 8;
    out[(size_t)n * CC + c0 + tx] = (__bf16)tile[tx][ty + i * 8];
  }
}

// fp32 -> bf16 weight conversion for the four 512x512 weights.
__global__ __launch_bounds__(256) void cvt_w(const float* __restrict__ w0, const float* __restrict__ w1,
                                             const float* __restrict__ w2, const float* __restrict__ w3,
                                             __bf16* __restrict__ o0, __bf16* __restrict__ o1,
                                             __bf16* __restrict__ o2, __bf16* __restrict__ o3) {
  int tsel = blockIdx.x >> 8;
  int i = (blockIdx.x & 255) * 256 + threadIdx.x;
  const float* src = tsel == 0 ? w0 : tsel == 1 ? w1 : tsel == 2 ? w2 : w3;
  __bf16* dst = tsel == 0 ? o0 : tsel == 1 ? o1 : tsel == 2 ? o2 : o3;
  float4 v = ((const float4*)src)[i];
  bf16_4 r;
  r[0] = (__bf16)v.x; r[1] = (__bf16)v.y; r[2] = (__bf16)v.z; r[3] = (__bf16)v.w;
  ((bf16_4*)dst)[i] = r;
}

// ======== Core A: 512 threads, 8 waves, 64x32/wave, BK=64 (round-7 best) ========
// Used by qkv/ao/wo (with LDS-repack epilogues). acc 4x2 = 32 AGPRs.
__device__ __forceinline__ void gemm_core8(const __bf16* __restrict__ A, const __bf16* __restrict__ B,
                                           int K, int lda, int ldb,
                                           __bf16* lA, __bf16* lB, f32_4 (&acc)[4][2]) {
  const int t = threadIdx.x;
  const int lane = t & 63;
  const int wave = t >> 6;
  const int lrow = lane & 15, quad = lane >> 4;
  const int wrow = (wave >> 2) * 64, wcol = (wave & 3) * 32;
  const int co = (quad ^ ((lrow >> 1) & 3)) * 8;   // swizzled read chunk
  const int r0 = t >> 2;                            // 0..127: staged row
  const int kp = ((t & 3) ^ ((t >> 3) & 3)) * 8;   // swizzled staged global chunk
  const __bf16* pA = A + (size_t)r0 * lda + kp;
  const __bf16* pB = B + (size_t)r0 * ldb + kp;
  for (int k0 = 0; k0 < K; k0 += 64) {
    __syncthreads();
    gld_lds16(pA + k0,      &lA[t * 8]);
    gld_lds16(pA + k0 + 32, &lA[4096 + t * 8]);
    gld_lds16(pB + k0,      &lB[t * 8]);
    gld_lds16(pB + k0 + 32, &lB[4096 + t * 8]);
    __syncthreads();
#pragma unroll
    for (int ks = 0; ks < 2; ks++) {
      const __bf16* la = lA + ks * 4096;
      const __bf16* lb = lB + ks * 4096;
      bf16_8 af[4], bfr[2];
#pragma unroll
      for (int i = 0; i < 4; i++)
        af[i] = *(const bf16_8*)&la[(wrow + i * 16 + lrow) * 32 + co];
#pragma unroll
      for (int j = 0; j < 2; j++)
        bfr[j] = *(const bf16_8*)&lb[(wcol + j * 16 + lrow) * 32 + co];
#pragma unroll
      for (int i = 0; i < 4; i++)
#pragma unroll
        for (int j = 0; j < 2; j++)
          acc[i][j] = __builtin_amdgcn_mfma_f32_16x16x32_bf16(af[i], bfr[j], acc[i][j], 0, 0, 0);
    }
  }
}

// Repack epilogue for core A (512 threads).
__device__ __forceinline__ void stage_acc8(float* ls, const f32_4 (&acc)[4][2], int pass) {
  const int t = threadIdx.x;
  const int lane = t & 63, wave = t >> 6;
  const int lrow = lane & 15, quad = lane >> 4;
  const int wrow = (wave >> 2) * 64, wcol = (wave & 3) * 32;
  if ((wrow >> 6) == pass) {
#pragma unroll
    for (int i = 0; i < 4; i++)
#pragma unroll
      for (int r = 0; r < 4; r++)
#pragma unroll
        for (int jj = 0; jj < 2; jj++)
          ls[(i * 16 + quad * 4 + r) * RSTRIDE + wcol + jj * 16 + lrow] = acc[i][jj][r];
  }
}

__device__ __forceinline__ void drain_bf16_8(const float* ls, __bf16* gdst, int ldg) {
  const int t = threadIdx.x;
#pragma unroll
  for (int k2 = 0; k2 < 4; k2++) {
    int idx = k2 * 512 + t;
    int row = idx >> 5, col = (idx & 31) * 4;
    f32_4 v = *(const f32_4*)&ls[row * RSTRIDE + col];
    bf16_4 o;
    o[0] = (__bf16)v[0]; o[1] = (__bf16)v[1]; o[2] = (__bf16)v[2]; o[3] = (__bf16)v[3];
    *(bf16_4*)&gdst[(size_t)row * ldg + col] = o;
  }
}

// ======== Core B: 256 threads, 4 waves, 64x64/wave, BK=64 (round-9 best for e_gemm) ========
// acc 4x4 = 64 AGPRs; max LDS reuse (16 MACs/byte).
__device__ __forceinline__ void gemm_core4(const __bf16* __restrict__ A, const __bf16* __restrict__ B,
                                           int K, int lda, int ldb,
                                           __bf16* lA, __bf16* lB, f32_4 (&acc)[4][4]) {
  const int t = threadIdx.x;
  const int lane = t & 63;
  const int wave = t >> 6;
  const int lrow = lane & 15, quad = lane >> 4;
  const int wrow = (wave >> 1) * 64, wcol = (wave & 1) * 64;
  const int co = (quad ^ ((lrow >> 1) & 3)) * 8;
  const int r0 = t >> 2;                            // 0..63
  const int kp = ((t & 3) ^ ((t >> 3) & 3)) * 8;
  const __bf16* pA0 = A + (size_t)r0 * lda + kp;
  const __bf16* pA1 = A + (size_t)(r0 + 64) * lda + kp;
  const __bf16* pB0 = B + (size_t)r0 * ldb + kp;
  const __bf16* pB1 = B + (size_t)(r0 + 64) * ldb + kp;
  for (int k0 = 0; k0 < K; k0 += 64) {
    __syncthreads();
    gld_lds16(pA0 + k0,      &lA[t * 8]);
    gld_lds16(pA1 + k0,      &lA[2048 + t * 8]);
    gld_lds16(pA0 + k0 + 32, &lA[4096 + t * 8]);
    gld_lds16(pA1 + k0 + 32, &lA[6144 + t * 8]);
    gld_lds16(pB0 + k0,      &lB[t * 8]);
    gld_lds16(pB1 + k0,      &lB[2048 + t * 8]);
    gld_lds16(pB0 + k0 + 32, &lB[4096 + t * 8]);
    gld_lds16(pB1 + k0 + 32, &lB[6144 + t * 8]);
    __syncthreads();
#pragma unroll
    for (int ks = 0; ks < 2; ks++) {
      const __bf16* la = lA + ks * 4096;
      const __bf16* lb = lB + ks * 4096;
      bf16_8 af[4], bfr[4];
#pragma unroll
      for (int i = 0; i < 4; i++)
        af[i] = *(const bf16_8*)&la[(wrow + i * 16 + lrow) * 32 + co];
#pragma unroll
      for (int j = 0; j < 4; j++)
        bfr[j] = *(const bf16_8*)&lb[(wcol + j * 16 + lrow) * 32 + co];
#pragma unroll
      for (int i = 0; i < 4; i++)
#pragma unroll
        for (int j = 0; j < 4; j++)
          acc[i][j] = __builtin_amdgcn_mfma_f32_16x16x32_bf16(af[i], bfr[j], acc[i][j], 0, 0, 0);
    }
  }
}

// ---------------- Fused Q/K/V projections (one dispatch, 768 blocks, core A) ----------
__global__ __launch_bounds__(512, 4) void qkv_gemm(const __bf16* __restrict__ hnT,
                                                   const __bf16* __restrict__ Wq,
                                                   const __bf16* __restrict__ Wk,
                                                   const __bf16* __restrict__ Wv,
                                                   const float* __restrict__ bq,
                                                   const float* __restrict__ bk,
                                                   const float* __restrict__ bv,
                                                   __bf16* __restrict__ qT,
                                                   __bf16* __restrict__ kT,
                                                   __bf16* __restrict__ vv) {
  __shared__ char smem[SMEM_BYTES];
  __bf16* lA = (__bf16*)smem;
  __bf16* lB = (__bf16*)(smem + 16384);
  float* lsr = (float*)smem;
  const int b = blockIdx.z;
  const int id = blockIdx.x;
  const int sel = id >> 7;
  const int r = id & 127;
  const long long sBNC = (long long)NS * CC;
  const long long sBCN = (long long)CC * NS;

  int m0, n0, N;
  const __bf16 *Ap, *Bp;
  __bf16* Cp;
  const float* bias;
  if (sel < 2) {  // q/k: out[n, o] = sum_c hnT[n,c] W[o,c] + b[o]
    m0 = (r >> 2) * TILE;
    n0 = (r & 3) * TILE;
    Ap = hnT + (size_t)b * sBNC + (size_t)m0 * CC;
    Bp = (sel == 0 ? Wq : Wk) + (size_t)n0 * CC;
    Cp = (sel == 0 ? qT : kT) + (size_t)b * sBNC;
    bias = (sel == 0 ? bq : bk);
    N = CC;
  } else {  // v: out[o, n] = sum_c Wv[o,c] hnT[n,c] + bv[o]
    m0 = (r & 3) * TILE;
    n0 = (r >> 2) * TILE;
    Ap = Wv + (size_t)m0 * CC;
    Bp = hnT + (size_t)b * sBNC + (size_t)n0 * CC;
    Cp = vv + (size_t)b * sBCN;
    bias = bv;
    N = NS;
  }

  f32_4 acc[4][2];
#pragma unroll
  for (int i = 0; i < 4; i++)
#pragma unroll
    for (int j = 0; j < 2; j++) acc[i][j] = {0.f, 0.f, 0.f, 0.f};

  gemm_core8(Ap, Bp, CC, CC, CC, lA, lB, acc);

  const int t = threadIdx.x;
  const int lane = t & 63;
  const int lrow = lane & 15, quad = lane >> 4;
  const int wave = t >> 6;
  const int wrow = (wave >> 2) * 64, wcol = (wave & 3) * 32;
#pragma unroll
  for (int i = 0; i < 4; i++)
#pragma unroll
    for (int r2 = 0; r2 < 4; r2++) {
      float rowb = (sel == 2) ? bias[m0 + wrow + i * 16 + quad * 4 + r2] : 0.f;
#pragma unroll
      for (int j = 0; j < 2; j++) {
        float cb = (sel < 2) ? bias[n0 + wcol + j * 16 + lrow] : rowb;
        acc[i][j][r2] += cb;
      }
    }

#pragma unroll
  for (int p = 0; p < 2; p++) {
    __syncthreads();
    stage_acc8(lsr, acc, p);
    __syncthreads();
    drain_bf16_8(lsr, Cp + (size_t)(m0 + p * 64) * N + n0, N);
  }
}

// ---------------- S-GEMM with fused exp + row-sum (core B, 2048 blocks) ---------------
// E[i,j] = exp(scale * sum_c qT[i,c] kT[j,c]) (bf16, unnormalized); l[i] += row
// sums (fp32 atomics). Division by l later = exact softmax. Scatter epilogue
// (measured faster than repack for this kernel). XCD swizzle: g&7 -> (b, m-octet).
__global__ __launch_bounds__(256) void e_gemm(const __bf16* __restrict__ qT,
                                              const __bf16* __restrict__ kT,
                                              __bf16* __restrict__ E,
                                              float* __restrict__ l,
                                              float scale) {
  __shared__ char smem[32768];
  __bf16* lA = (__bf16*)smem;
  __bf16* lB = (__bf16*)(smem + 16384);
  const int g = blockIdx.x;
  const int j = g & 7;
  const int b = j & 1;
  const int moct = j >> 1;        // 0..3
  const int k = g >> 3;           // 0..255
  const int sc = k >> 6;          // n-supercolumn 0..3
  const int rem = k & 63;
  const int m0 = (moct * 8 + (rem >> 3)) * TILE;
  const int n0 = (sc * 8 + (rem & 7)) * TILE;
  const long long sBNC = (long long)NS * CC;
  const long long sBNN = (long long)NS * NS;
  const __bf16* Ap = qT + (size_t)b * sBNC + (size_t)m0 * CC;
  const __bf16* Bp = kT + (size_t)b * sBNC + (size_t)n0 * CC;

  f32_4 acc[4][4];
#pragma unroll
  for (int i = 0; i < 4; i++)
#pragma unroll
    for (int jj = 0; jj < 4; jj++) acc[i][jj] = {0.f, 0.f, 0.f, 0.f};

  gemm_core4(Ap, Bp, CC, CC, CC, lA, lB, acc);

  const int t = threadIdx.x;
  const int lane = t & 63;
  const int lrow = lane & 15, quad = lane >> 4;
  const int wave = t >> 6;
  const int wrow = (wave >> 1) * 64, wcol = (wave & 1) * 64;
  __bf16* Ep = E + (size_t)b * sBNN;
  float* lp = l + (size_t)b * NS;
#pragma unroll
  for (int i = 0; i < 4; i++) {
#pragma unroll
    for (int r = 0; r < 4; r++) {
      int gm = m0 + wrow + i * 16 + quad * 4 + r;
      float rp = 0.f;
#pragma unroll
      for (int jj = 0; jj < 4; jj++) {
        int gn = n0 + wcol + jj * 16 + lrow;
        float ev = __expf(acc[i][jj][r] * scale);
        rp += ev;
        Ep[(size_t)gm * NS + gn] = (__bf16)ev;
      }
      rp += __shfl_down(rp, 8, 16);
      rp += __shfl_down(rp, 4, 16);
      rp += __shfl_down(rp, 2, 16);
      rp += __shfl_down(rp, 1, 16);
      if (lrow == 0) atomicAdd(&lp[gm], rp);
    }
  }
}

// ---------------- attn*V split-K=4 GEMM (1024 blocks, XCD-swizzled, core A) ----------
__global__ __launch_bounds__(512, 4) void ao_split4(const __bf16* __restrict__ E,
                                                    const __bf16* __restrict__ vv,
                                                    __bf16* __restrict__ p0,
                                                    __bf16* __restrict__ p1,
                                                    __bf16* __restrict__ p2,
                                                    __bf16* __restrict__ p3) {
  __shared__ char smem[SMEM_BYTES];
  __bf16* lA = (__bf16*)smem;
  __bf16* lB = (__bf16*)(smem + 16384);
  float* lsr = (float*)smem;
  const int g = blockIdx.x;
  const int j = g & 7;
  const int b = j & 1;
  const int split = j >> 1;
  const int k = g >> 3;            // 0..127
  const int m0 = (k >> 2) * TILE;  // over NS (i), 32 tiles
  const int n0 = (k & 3) * TILE;   // over CC (c), 4 tiles
  const long long sBNN = (long long)NS * NS;
  const long long sBCN = (long long)CC * NS;
  const long long sBNC = (long long)NS * CC;
  const __bf16* Ap = E + (size_t)b * sBNN + (size_t)m0 * NS + (size_t)split * 1024;
  const __bf16* Bp = vv + (size_t)b * sBCN + (size_t)n0 * NS + (size_t)split * 1024;
  __bf16* Cp = (split == 0 ? p0 : split == 1 ? p1 : split == 2 ? p2 : p3) + (size_t)b * sBNC;

  f32_4 acc[4][2];
#pragma unroll
  for (int i = 0; i < 4; i++)
#pragma unroll
    for (int jj = 0; jj < 2; jj++) acc[i][jj] = {0.f, 0.f, 0.f, 0.f};

  gemm_core8(Ap, Bp, 1024, NS, NS, lA, lB, acc);

#pragma unroll
  for (int p = 0; p < 2; p++) {
    __syncthreads();
    stage_acc8(lsr, acc, p);
    __syncthreads();
    drain_bf16_8(lsr, Cp + (size_t)(m0 + p * 64) * CC + n0, CC);
  }
}

// (p0+p1+p2+p3)/l[row] -> aoT (bf16). p3 may alias the output (elementwise RAW).
__global__ __launch_bounds__(256) void reduce_ao4(const __bf16* __restrict__ p0,
                                                  const __bf16* __restrict__ p1,
                                                  const __bf16* __restrict__ p2,
                                                  const __bf16* __restrict__ p3,
                                                  const float* __restrict__ l,
                                                  __bf16* __restrict__ o) {
  int i = blockIdx.x * 256 + threadIdx.x;   // bf16_8 units, [B][NS][CC]
  int row = i >> 6;                          // 64 vecs per row of 512 chans
  float inv = 1.f / l[row];
  bf16_8 a = ((const bf16_8*)p0)[i];
  bf16_8 c = ((const bf16_8*)p1)[i];
  bf16_8 d = ((const bf16_8*)p2)[i];
  bf16_8 e = ((const bf16_8*)p3)[i];
  bf16_8 r;
#pragma unroll
  for (int k = 0; k < 8; k++)
    r[k] = (__bf16)(((float)a[k] + (float)c[k] + (float)d[k] + (float)e[k]) * inv);
  ((bf16_8*)o)[i] = r;
}

// ---------------- Output projection, split-K=2, bf16 partials (core A) ----------------
__global__ __launch_bounds__(512, 4) void wo_split(const __bf16* __restrict__ Wo,
                                                   const __bf16* __restrict__ aoT,
                                                   __bf16* __restrict__ pw0,
                                                   __bf16* __restrict__ pw1) {
  __shared__ char smem[SMEM_BYTES];
  __bf16* lA = (__bf16*)smem;
  __bf16* lB = (__bf16*)(smem + 16384);
  float* lsr = (float*)smem;
  const int b = blockIdx.z & 1;
  const int split = blockIdx.z >> 1;
  const int m0 = blockIdx.y * TILE;   // over CC (o)
  const int n0 = blockIdx.x * TILE;   // over NS (n)
  const long long sBNC = (long long)NS * CC;
  const long long sBCN = (long long)CC * NS;
  const __bf16* Ap = Wo + (size_t)m0 * CC + (size_t)split * 256;
  const __bf16* Bp = aoT + (size_t)b * sBNC + (size_t)n0 * CC + (size_t)split * 256;
  __bf16* Cp = (split ? pw1 : pw0) + (size_t)b * sBCN;

  f32_4 acc[4][2];
#pragma unroll
  for (int i = 0; i < 4; i++)
#pragma unroll
    for (int j = 0; j < 2; j++) acc[i][j] = {0.f, 0.f, 0.f, 0.f};

  gemm_core8(Ap, Bp, 256, CC, CC, lA, lB, acc);

#pragma unroll
  for (int p = 0; p < 2; p++) {
    __syncthreads();
    stage_acc8(lsr, acc, p);
    __syncthreads();
    drain_bf16_8(lsr, Cp + (size_t)(m0 + p * 64) * NS + n0, NS);
  }
}

// out = pw0 + pw1 + bo[o] + x   (bf16 partials, fp32 out, vectorized)
__global__ __launch_bounds__(256) void final_out(const __bf16* __restrict__ pw0,
                                                 const __bf16* __restrict__ pw1,
                                                 const float* __restrict__ bo,
                                                 const float* __restrict__ x,
                                                 float* __restrict__ out) {
  int i = blockIdx.x * 256 + threadIdx.x;   // 4-elem units over [B][CC][NS]
  int o = (i >> 10) & (CC - 1);             // 1024 units per channel-row
  float bias = bo[o];
  bf16_4 a = ((const bf16_4*)pw0)[i];
  bf16_4 c = ((const bf16_4*)pw1)[i];
  float4 xr = ((const float4*)x)[i];
  float4 r;
  r.x = (float)a[0] + (float)c[0] + bias + xr.x;
  r.y = (float)a[1] + (float)c[1] + bias + xr.y;
  r.z = (float)a[2] + (float)c[2] + bias + xr.z;
  r.w = (float)a[3] + (float)c[3] + bias + xr.w;
  ((float4*)out)[i] = r;
}

extern "C" void kernel_launch(void* const* d_in, const int* in_sizes, int n_in,
                              void* d_out, int out_size, void* d_ws, size_t ws_size,
                              hipStream_t stream) {
  const float* x = (const float*)d_in[0];
  const float* gamma = (const float*)d_in[1];
  const float* beta = (const float*)d_in[2];
  const float* Wq = (const float*)d_in[3];
  const float* bq = (const float*)d_in[4];
  const float* Wk = (const float*)d_in[5];
  const float* bk = (const float*)d_in[6];
  const float* Wv = (const float*)d_in[7];
  const float* bv = (const float*)d_in[8];
  const float* Wo = (const float*)d_in[9];
  const float* bo = (const float*)d_in[10];
  float* out = (float*)d_out;

  char* ws = (char*)d_ws;
  __bf16* hnT = (__bf16*)(ws + 0);           // [B][NS][CC] 8 MiB; later ao partial p0
  __bf16* qT  = (__bf16*)(ws + 8388608);     // later p1
  __bf16* kT  = (__bf16*)(ws + 16777216);    // later p2
  __bf16* vv  = (__bf16*)(ws + 25165824);    // [B][CC][NS]
  __bf16* aoT = (__bf16*)(ws + 33554432);    // [B][NS][CC]; doubles as p3 (RAW-safe)
  __bf16* Eb  = (__bf16*)(ws + 41943040);    // [B][NS][NS] 64 MiB; later wo partials
  __bf16* pw0 = (__bf16*)(ws + 41943040);    // 8 MiB (inside dead E region)
  __bf16* pw1 = (__bf16*)(ws + 50331648);    // 8 MiB
  __bf16* Wqb = (__bf16*)(ws + 109051904);   // dead after qkv -> reused as lsum
  __bf16* Wkb = (__bf16*)(ws + 109576192);
  __bf16* Wvb = (__bf16*)(ws + 110100480);
  __bf16* Wob = (__bf16*)(ws + 110624768);
  float* stats = (float*)(ws + 111149056);
  float* lsum = (float*)(ws + 109051904);    // [B][NS] fp32, aliases dead Wqb
  __bf16* p0 = hnT;
  __bf16* p1 = qT;
  __bf16* p2 = kT;
  __bf16* p3 = aoT;

  const float scale = 0.044194173824159216f;  // 512^-0.5

  cvt_w<<<1024, 256, 0, stream>>>(Wq, Wk, Wv, Wo, Wqb, Wkb, Wvb, Wob);
  gn_stats<<<BB * NGROUP, 256, 0, stream>>>(x, stats);
  gn_apply_t<<<dim3(NS / 32, CC / 32, BB), dim3(32, 8), 0, stream>>>(x, stats, gamma, beta, hnT);

  // Fused Q/K/V projections: 768 blocks (core A).
  qkv_gemm<<<dim3(384, 1, BB), 512, 0, stream>>>(hnT, Wqb, Wkb, Wvb, bq, bk, bv, qT, kT, vv);

  // Zero row-sum accumulator (Wqb is dead now), then E-GEMM (core B).
  hipMemsetAsync(lsum, 0, BB * NS * sizeof(float), stream);
  e_gemm<<<2048, 256, 0, stream>>>(qT, kT, Eb, lsum, scale);

  // aoT partials = E * v^T over quarter-K splits (1024 blocks, core A).
  ao_split4<<<1024, 512, 0, stream>>>(Eb, vv, p0, p1, p2, p3);
  reduce_ao4<<<2048, 256, 0, stream>>>(p0, p1, p2, p3, lsum, aoT);

  // Output projection split-K=2 (512 blocks, core A, bf16 partials) + fused epilogue.
  wo_split<<<dim3(NS / TILE, CC / TILE, 2 * BB), 512, 0, stream>>>(Wob, aoT, pw0, pw1);
  final_out<<<4096, 256, 0, stream>>>(pw0, pw1, bo, x, out);
}

// Round 11
// 244.351 us; speedup vs baseline: 1.1088x; 1.0570x over previous
//
#include <hip/hip_runtime.h>

// Problem constants: x [B=2, C=512, H=64, W=64], 32 groups, N = H*W = 4096.
#define BB 2
#define CC 512
#define NS 4096
#define NGROUP 32
#define TILE 128
#define RSTRIDE 132   // repack LDS row stride (floats): 128 + 4 pad

typedef __bf16 bf16_8 __attribute__((ext_vector_type(8)));
typedef __bf16 bf16_4 __attribute__((ext_vector_type(4)));
typedef float f32_4 __attribute__((ext_vector_type(4)));

#define SMEM_BYTES 65536   // 2 x (16KB A + 16KB B) double-buffer; repack unions in

__device__ __forceinline__ void gld_lds16(const __bf16* g, __bf16* l) {
  __builtin_amdgcn_global_load_lds(
      (const __attribute__((address_space(1))) unsigned int*)g,
      (__attribute__((address_space(3))) unsigned int*)l, 16, 0, 0);
}

// ---------------- GroupNorm ----------------
__global__ __launch_bounds__(256) void gn_stats(const float* __restrict__ x,
                                                float* __restrict__ stats) {
  const float4* p = (const float4*)(x + (size_t)blockIdx.x * 65536);
  float s = 0.f, q = 0.f;
  for (int i = threadIdx.x; i < 16384; i += 256) {
    float4 v = p[i];
    s += v.x + v.y + v.z + v.w;
    q += v.x * v.x + v.y * v.y + v.z * v.z + v.w * v.w;
  }
#pragma unroll
  for (int off = 32; off > 0; off >>= 1) {
    s += __shfl_down(s, off, 64);
    q += __shfl_down(q, off, 64);
  }
  __shared__ float ls[4], lq[4];
  int wave = threadIdx.x >> 6, lane = threadIdx.x & 63;
  if (lane == 0) { ls[wave] = s; lq[wave] = q; }
  __syncthreads();
  if (threadIdx.x == 0) {
    float S = ls[0] + ls[1] + ls[2] + ls[3];
    float Q = lq[0] + lq[1] + lq[2] + lq[3];
    float mean = S * (1.f / 65536.f);
    float var = Q * (1.f / 65536.f) - mean * mean;
    stats[blockIdx.x * 2] = mean;
    stats[blockIdx.x * 2 + 1] = rsqrtf(var + 1e-6f);
  }
}

// Normalize + transpose: x[b][c][n] (fp32) -> hnT[b][n][c] (bf16), 32x32 tiles via LDS.
__global__ __launch_bounds__(256) void gn_apply_t(const float* __restrict__ x,
                                                  const float* __restrict__ stats,
                                                  const float* __restrict__ gamma,
                                                  const float* __restrict__ beta,
                                                  __bf16* __restrict__ hnT) {
  __shared__ float tile[32][33];
  int b = blockIdx.z;
  int c0 = blockIdx.y * 32;
  int n0 = blockIdx.x * 32;
  int tx = threadIdx.x;  // 0..31
  int ty = threadIdx.y;  // 0..7
  const float* xb = x + (size_t)b * CC * NS;
#pragma unroll
  for (int i = 0; i < 4; i++) {
    int c = c0 + ty + i * 8;
    float mean = stats[(b * NGROUP + (c >> 4)) * 2 + 0];
    float rstd = stats[(b * NGROUP + (c >> 4)) * 2 + 1];
    float v = xb[(size_t)c * NS + n0 + tx];
    tile[ty + i * 8][tx] = (v - mean) * rstd * gamma[c] + beta[c];
  }
  __syncthreads();
  __bf16* out = hnT + (size_t)b * NS * CC;
#pragma unroll
  for (int i = 0; i < 4; i++) {
    int n = n0 + ty + i * 8;
    out[(size_t)n * CC + c0 + tx] = (__bf16)tile[tx][ty + i * 8];
  }
}

// fp32 -> bf16 weight conversion for the four 512x512 weights.
__global__ __launch_bounds__(256) void cvt_w(const float* __restrict__ w0, const float* __restrict__ w1,
                                             const float* __restrict__ w2, const float* __restrict__ w3,
                                             __bf16* __restrict__ o0, __bf16* __restrict__ o1,
                                             __bf16* __restrict__ o2, __bf16* __restrict__ o3) {
  int tsel = blockIdx.x >> 8;
  int i = (blockIdx.x & 255) * 256 + threadIdx.x;
  const float* src = tsel == 0 ? w0 : tsel == 1 ? w1 : tsel == 2 ? w2 : w3;
  __bf16* dst = tsel == 0 ? o0 : tsel == 1 ? o1 : tsel == 2 ? o2 : o3;
  float4 v = ((const float4*)src)[i];
  bf16_4 r;
  r[0] = (__bf16)v.x; r[1] = (__bf16)v.y; r[2] = (__bf16)v.z; r[3] = (__bf16)v.w;
  ((bf16_4*)dst)[i] = r;
}

// ======== Core A (double-buffered): 512 threads, 8 waves, 64x32/wave, BK=64 ========
// One barrier per K-iteration: barrier -> prefetch next tile into buf^1 ->
// compute buf. The vmcnt(0) drain at the NEXT barrier hits loads that had a
// full compute phase (~1500 cyc) to land, instead of being drained right
// after issue (the old 2-barrier structure exposed full L2 latency per iter).
// Buffer layout (bf16 elems): buf b: A at b*16384, B at b*16384+8192.
__device__ __forceinline__ void gemm_core8(const __bf16* __restrict__ A, const __bf16* __restrict__ B,
                                           int K, int lda, int ldb,
                                           __bf16* lds, f32_4 (&acc)[4][2]) {
  const int t = threadIdx.x;
  const int lane = t & 63;
  const int wave = t >> 6;
  const int lrow = lane & 15, quad = lane >> 4;
  const int wrow = (wave >> 2) * 64, wcol = (wave & 3) * 32;
  const int co = (quad ^ ((lrow >> 1) & 3)) * 8;   // swizzled read chunk
  const int r0 = t >> 2;                            // 0..127: staged row
  const int kp = ((t & 3) ^ ((t >> 3) & 3)) * 8;   // swizzled staged global chunk
  const __bf16* pA = A + (size_t)r0 * lda + kp;
  const __bf16* pB = B + (size_t)r0 * ldb + kp;
  // prologue: stage k0=0 into buf0
  {
    __bf16* lA = lds;
    __bf16* lB = lds + 8192;
    gld_lds16(pA,      &lA[t * 8]);
    gld_lds16(pA + 32, &lA[4096 + t * 8]);
    gld_lds16(pB,      &lB[t * 8]);
    gld_lds16(pB + 32, &lB[4096 + t * 8]);
  }
  int buf = 0;
  for (int k0 = 0; k0 < K; k0 += 64, buf ^= 1) {
    __syncthreads();   // drains buf's loads (prefetched last iter); protects buf^1 overwrite
    if (k0 + 64 < K) {
      __bf16* lA = lds + (buf ^ 1) * 16384;
      __bf16* lB = lA + 8192;
      gld_lds16(pA + k0 + 64, &lA[t * 8]);
      gld_lds16(pA + k0 + 96, &lA[4096 + t * 8]);
      gld_lds16(pB + k0 + 64, &lB[t * 8]);
      gld_lds16(pB + k0 + 96, &lB[4096 + t * 8]);
    }
    const __bf16* bA = lds + buf * 16384;
    const __bf16* bB = bA + 8192;
#pragma unroll
    for (int ks = 0; ks < 2; ks++) {
      const __bf16* la = bA + ks * 4096;
      const __bf16* lb = bB + ks * 4096;
      bf16_8 af[4], bfr[2];
#pragma unroll
      for (int i = 0; i < 4; i++)
        af[i] = *(const bf16_8*)&la[(wrow + i * 16 + lrow) * 32 + co];
#pragma unroll
      for (int j = 0; j < 2; j++)
        bfr[j] = *(const bf16_8*)&lb[(wcol + j * 16 + lrow) * 32 + co];
#pragma unroll
      for (int i = 0; i < 4; i++)
#pragma unroll
        for (int j = 0; j < 2; j++)
          acc[i][j] = __builtin_amdgcn_mfma_f32_16x16x32_bf16(af[i], bfr[j], acc[i][j], 0, 0, 0);
    }
  }
}

// Repack epilogue for core A (512 threads). lsr unions with dead staging LDS.
__device__ __forceinline__ void stage_acc8(float* ls, const f32_4 (&acc)[4][2], int pass) {
  const int t = threadIdx.x;
  const int lane = t & 63, wave = t >> 6;
  const int lrow = lane & 15, quad = lane >> 4;
  const int wrow = (wave >> 2) * 64, wcol = (wave & 3) * 32;
  if ((wrow >> 6) == pass) {
#pragma unroll
    for (int i = 0; i < 4; i++)
#pragma unroll
      for (int r = 0; r < 4; r++)
#pragma unroll
        for (int jj = 0; jj < 2; jj++)
          ls[(i * 16 + quad * 4 + r) * RSTRIDE + wcol + jj * 16 + lrow] = acc[i][jj][r];
  }
}

__device__ __forceinline__ void drain_bf16_8(const float* ls, __bf16* gdst, int ldg) {
  const int t = threadIdx.x;
#pragma unroll
  for (int k2 = 0; k2 < 4; k2++) {
    int idx = k2 * 512 + t;
    int row = idx >> 5, col = (idx & 31) * 4;
    f32_4 v = *(const f32_4*)&ls[row * RSTRIDE + col];
    bf16_4 o;
    o[0] = (__bf16)v[0]; o[1] = (__bf16)v[1]; o[2] = (__bf16)v[2]; o[3] = (__bf16)v[3];
    *(bf16_4*)&gdst[(size_t)row * ldg + col] = o;
  }
}

// ======== Core B (double-buffered): 256 threads, 4 waves, 64x64/wave, BK=64 ========
// acc 4x4 = 64 AGPRs; max LDS reuse. Same one-barrier prefetch structure.
__device__ __forceinline__ void gemm_core4(const __bf16* __restrict__ A, const __bf16* __restrict__ B,
                                           int K, int lda, int ldb,
                                           __bf16* lds, f32_4 (&acc)[4][4]) {
  const int t = threadIdx.x;
  const int lane = t & 63;
  const int wave = t >> 6;
  const int lrow = lane & 15, quad = lane >> 4;
  const int wrow = (wave >> 1) * 64, wcol = (wave & 1) * 64;
  const int co = (quad ^ ((lrow >> 1) & 3)) * 8;
  const int r0 = t >> 2;                            // 0..63
  const int kp = ((t & 3) ^ ((t >> 3) & 3)) * 8;
  const __bf16* pA0 = A + (size_t)r0 * lda + kp;
  const __bf16* pA1 = A + (size_t)(r0 + 64) * lda + kp;
  const __bf16* pB0 = B + (size_t)r0 * ldb + kp;
  const __bf16* pB1 = B + (size_t)(r0 + 64) * ldb + kp;
  // prologue: stage k0=0 into buf0
  {
    __bf16* lA = lds;
    __bf16* lB = lds + 8192;
    gld_lds16(pA0,      &lA[t * 8]);
    gld_lds16(pA1,      &lA[2048 + t * 8]);
    gld_lds16(pA0 + 32, &lA[4096 + t * 8]);
    gld_lds16(pA1 + 32, &lA[6144 + t * 8]);
    gld_lds16(pB0,      &lB[t * 8]);
    gld_lds16(pB1,      &lB[2048 + t * 8]);
    gld_lds16(pB0 + 32, &lB[4096 + t * 8]);
    gld_lds16(pB1 + 32, &lB[6144 + t * 8]);
  }
  int buf = 0;
  for (int k0 = 0; k0 < K; k0 += 64, buf ^= 1) {
    __syncthreads();
    if (k0 + 64 < K) {
      __bf16* lA = lds + (buf ^ 1) * 16384;
      __bf16* lB = lA + 8192;
      gld_lds16(pA0 + k0 + 64, &lA[t * 8]);
      gld_lds16(pA1 + k0 + 64, &lA[2048 + t * 8]);
      gld_lds16(pA0 + k0 + 96, &lA[4096 + t * 8]);
      gld_lds16(pA1 + k0 + 96, &lA[6144 + t * 8]);
      gld_lds16(pB0 + k0 + 64, &lB[t * 8]);
      gld_lds16(pB1 + k0 + 64, &lB[2048 + t * 8]);
      gld_lds16(pB0 + k0 + 96, &lB[4096 + t * 8]);
      gld_lds16(pB1 + k0 + 96, &lB[6144 + t * 8]);
    }
    const __bf16* bA = lds + buf * 16384;
    const __bf16* bB = bA + 8192;
#pragma unroll
    for (int ks = 0; ks < 2; ks++) {
      const __bf16* la = bA + ks * 4096;
      const __bf16* lb = bB + ks * 4096;
      bf16_8 af[4], bfr[4];
#pragma unroll
      for (int i = 0; i < 4; i++)
        af[i] = *(const bf16_8*)&la[(wrow + i * 16 + lrow) * 32 + co];
#pragma unroll
      for (int j = 0; j < 4; j++)
        bfr[j] = *(const bf16_8*)&lb[(wcol + j * 16 + lrow) * 32 + co];
#pragma unroll
      for (int i = 0; i < 4; i++)
#pragma unroll
        for (int j = 0; j < 4; j++)
          acc[i][j] = __builtin_amdgcn_mfma_f32_16x16x32_bf16(af[i], bfr[j], acc[i][j], 0, 0, 0);
    }
  }
}

// ---------------- Fused Q/K/V projections (one dispatch, 768 blocks, core A) ----------
__global__ __launch_bounds__(512, 4) void qkv_gemm(const __bf16* __restrict__ hnT,
                                                   const __bf16* __restrict__ Wq,
                                                   const __bf16* __restrict__ Wk,
                                                   const __bf16* __restrict__ Wv,
                                                   const float* __restrict__ bq,
                                                   const float* __restrict__ bk,
                                                   const float* __restrict__ bv,
                                                   __bf16* __restrict__ qT,
                                                   __bf16* __restrict__ kT,
                                                   __bf16* __restrict__ vv) {
  __shared__ char smem[SMEM_BYTES];
  __bf16* lds = (__bf16*)smem;
  float* lsr = (float*)smem;
  const int b = blockIdx.z;
  const int id = blockIdx.x;
  const int sel = id >> 7;
  const int r = id & 127;
  const long long sBNC = (long long)NS * CC;
  const long long sBCN = (long long)CC * NS;

  int m0, n0, N;
  const __bf16 *Ap, *Bp;
  __bf16* Cp;
  const float* bias;
  if (sel < 2) {  // q/k: out[n, o] = sum_c hnT[n,c] W[o,c] + b[o]
    m0 = (r >> 2) * TILE;
    n0 = (r & 3) * TILE;
    Ap = hnT + (size_t)b * sBNC + (size_t)m0 * CC;
    Bp = (sel == 0 ? Wq : Wk) + (size_t)n0 * CC;
    Cp = (sel == 0 ? qT : kT) + (size_t)b * sBNC;
    bias = (sel == 0 ? bq : bk);
    N = CC;
  } else {  // v: out[o, n] = sum_c Wv[o,c] hnT[n,c] + bv[o]
    m0 = (r & 3) * TILE;
    n0 = (r >> 2) * TILE;
    Ap = Wv + (size_t)m0 * CC;
    Bp = hnT + (size_t)b * sBNC + (size_t)n0 * CC;
    Cp = vv + (size_t)b * sBCN;
    bias = bv;
    N = NS;
  }

  f32_4 acc[4][2];
#pragma unroll
  for (int i = 0; i < 4; i++)
#pragma unroll
    for (int j = 0; j < 2; j++) acc[i][j] = {0.f, 0.f, 0.f, 0.f};

  gemm_core8(Ap, Bp, CC, CC, CC, lds, acc);

  const int t = threadIdx.x;
  const int lane = t & 63;
  const int lrow = lane & 15, quad = lane >> 4;
  const int wave = t >> 6;
  const int wrow = (wave >> 2) * 64, wcol = (wave & 3) * 32;
#pragma unroll
  for (int i = 0; i < 4; i++)
#pragma unroll
    for (int r2 = 0; r2 < 4; r2++) {
      float rowb = (sel == 2) ? bias[m0 + wrow + i * 16 + quad * 4 + r2] : 0.f;
#pragma unroll
      for (int j = 0; j < 2; j++) {
        float cb = (sel < 2) ? bias[n0 + wcol + j * 16 + lrow] : rowb;
        acc[i][j][r2] += cb;
      }
    }

#pragma unroll
  for (int p = 0; p < 2; p++) {
    __syncthreads();
    stage_acc8(lsr, acc, p);
    __syncthreads();
    drain_bf16_8(lsr, Cp + (size_t)(m0 + p * 64) * N + n0, N);
  }
}

// ---------------- S-GEMM with fused exp + row-sum (core B, 2048 blocks) ---------------
// E[i,j] = exp(scale * sum_c qT[i,c] kT[j,c]) (bf16, unnormalized); l[i] += row
// sums (fp32 atomics). Division by l later = exact softmax. Scatter epilogue
// (measured faster than repack here). XCD swizzle: g&7 -> (b, m-octet).
__global__ __launch_bounds__(256) void e_gemm(const __bf16* __restrict__ qT,
                                              const __bf16* __restrict__ kT,
                                              __bf16* __restrict__ E,
                                              float* __restrict__ l,
                                              float scale) {
  __shared__ char smem[SMEM_BYTES];
  __bf16* lds = (__bf16*)smem;
  const int g = blockIdx.x;
  const int j = g & 7;
  const int b = j & 1;
  const int moct = j >> 1;        // 0..3
  const int k = g >> 3;           // 0..255
  const int sc = k >> 6;          // n-supercolumn 0..3
  const int rem = k & 63;
  const int m0 = (moct * 8 + (rem >> 3)) * TILE;
  const int n0 = (sc * 8 + (rem & 7)) * TILE;
  const long long sBNC = (long long)NS * CC;
  const long long sBNN = (long long)NS * NS;
  const __bf16* Ap = qT + (size_t)b * sBNC + (size_t)m0 * CC;
  const __bf16* Bp = kT + (size_t)b * sBNC + (size_t)n0 * CC;

  f32_4 acc[4][4];
#pragma unroll
  for (int i = 0; i < 4; i++)
#pragma unroll
    for (int jj = 0; jj < 4; jj++) acc[i][jj] = {0.f, 0.f, 0.f, 0.f};

  gemm_core4(Ap, Bp, CC, CC, CC, lds, acc);

  const int t = threadIdx.x;
  const int lane = t & 63;
  const int lrow = lane & 15, quad = lane >> 4;
  const int wave = t >> 6;
  const int wrow = (wave >> 1) * 64, wcol = (wave & 1) * 64;
  __bf16* Ep = E + (size_t)b * sBNN;
  float* lp = l + (size_t)b * NS;
#pragma unroll
  for (int i = 0; i < 4; i++) {
#pragma unroll
    for (int r = 0; r < 4; r++) {
      int gm = m0 + wrow + i * 16 + quad * 4 + r;
      float rp = 0.f;
#pragma unroll
      for (int jj = 0; jj < 4; jj++) {
        int gn = n0 + wcol + jj * 16 + lrow;
        float ev = __expf(acc[i][jj][r] * scale);
        rp += ev;
        Ep[(size_t)gm * NS + gn] = (__bf16)ev;
      }
      rp += __shfl_down(rp, 8, 16);
      rp += __shfl_down(rp, 4, 16);
      rp += __shfl_down(rp, 2, 16);
      rp += __shfl_down(rp, 1, 16);
      if (lrow == 0) atomicAdd(&lp[gm], rp);
    }
  }
}

// ---------------- attn*V split-K=4 GEMM (1024 blocks, XCD-swizzled, core A) ----------
__global__ __launch_bounds__(512, 4) void ao_split4(const __bf16* __restrict__ E,
                                                    const __bf16* __restrict__ vv,
                                                    __bf16* __restrict__ p0,
                                                    __bf16* __restrict__ p1,
                                                    __bf16* __restrict__ p2,
                                                    __bf16* __restrict__ p3) {
  __shared__ char smem[SMEM_BYTES];
  __bf16* lds = (__bf16*)smem;
  float* lsr = (float*)smem;
  const int g = blockIdx.x;
  const int j = g & 7;
  const int b = j & 1;
  const int split = j >> 1;
  const int k = g >> 3;            // 0..127
  const int m0 = (k >> 2) * TILE;  // over NS (i), 32 tiles
  const int n0 = (k & 3) * TILE;   // over CC (c), 4 tiles
  const long long sBNN = (long long)NS * NS;
  const long long sBCN = (long long)CC * NS;
  const long long sBNC = (long long)NS * CC;
  const __bf16* Ap = E + (size_t)b * sBNN + (size_t)m0 * NS + (size_t)split * 1024;
  const __bf16* Bp = vv + (size_t)b * sBCN + (size_t)n0 * NS + (size_t)split * 1024;
  __bf16* Cp = (split == 0 ? p0 : split == 1 ? p1 : split == 2 ? p2 : p3) + (size_t)b * sBNC;

  f32_4 acc[4][2];
#pragma unroll
  for (int i = 0; i < 4; i++)
#pragma unroll
    for (int jj = 0; jj < 2; jj++) acc[i][jj] = {0.f, 0.f, 0.f, 0.f};

  gemm_core8(Ap, Bp, 1024, NS, NS, lds, acc);

#pragma unroll
  for (int p = 0; p < 2; p++) {
    __syncthreads();
    stage_acc8(lsr, acc, p);
    __syncthreads();
    drain_bf16_8(lsr, Cp + (size_t)(m0 + p * 64) * CC + n0, CC);
  }
}

// (p0+p1+p2+p3)/l[row] -> aoT (bf16). p3 may alias the output (elementwise RAW).
__global__ __launch_bounds__(256) void reduce_ao4(const __bf16* __restrict__ p0,
                                                  const __bf16* __restrict__ p1,
                                                  const __bf16* __restrict__ p2,
                                                  const __bf16* __restrict__ p3,
                                                  const float* __restrict__ l,
                                                  __bf16* __restrict__ o) {
  int i = blockIdx.x * 256 + threadIdx.x;   // bf16_8 units, [B][NS][CC]
  int row = i >> 6;                          // 64 vecs per row of 512 chans
  float inv = 1.f / l[row];
  bf16_8 a = ((const bf16_8*)p0)[i];
  bf16_8 c = ((const bf16_8*)p1)[i];
  bf16_8 d = ((const bf16_8*)p2)[i];
  bf16_8 e = ((const bf16_8*)p3)[i];
  bf16_8 r;
#pragma unroll
  for (int k = 0; k < 8; k++)
    r[k] = (__bf16)(((float)a[k] + (float)c[k] + (float)d[k] + (float)e[k]) * inv);
  ((bf16_8*)o)[i] = r;
}

// ---------------- Output projection, split-K=2, bf16 partials (core A) ----------------
__global__ __launch_bounds__(512, 4) void wo_split(const __bf16* __restrict__ Wo,
                                                   const __bf16* __restrict__ aoT,
                                                   __bf16* __restrict__ pw0,
                                                   __bf16* __restrict__ pw1) {
  __shared__ char smem[SMEM_BYTES];
  __bf16* lds = (__bf16*)smem;
  float* lsr = (float*)smem;
  const int b = blockIdx.z & 1;
  const int split = blockIdx.z >> 1;
  const int m0 = blockIdx.y * TILE;   // over CC (o)
  const int n0 = blockIdx.x * TILE;   // over NS (n)
  const long long sBNC = (long long)NS * CC;
  const long long sBCN = (long long)CC * NS;
  const __bf16* Ap = Wo + (size_t)m0 * CC + (size_t)split * 256;
  const __bf16* Bp = aoT + (size_t)b * sBNC + (size_t)n0 * CC + (size_t)split * 256;
  __bf16* Cp = (split ? pw1 : pw0) + (size_t)b * sBCN;

  f32_4 acc[4][2];
#pragma unroll
  for (int i = 0; i < 4; i++)
#pragma unroll
    for (int j = 0; j < 2; j++) acc[i][j] = {0.f, 0.f, 0.f, 0.f};

  gemm_core8(Ap, Bp, 256, CC, CC, lds, acc);

#pragma unroll
  for (int p = 0; p < 2; p++) {
    __syncthreads();
    stage_acc8(lsr, acc, p);
    __syncthreads();
    drain_bf16_8(lsr, Cp + (size_t)(m0 + p * 64) * NS + n0, NS);
  }
}

// out = pw0 + pw1 + bo[o] + x   (bf16 partials, fp32 out, vectorized)
__global__ __launch_bounds__(256) void final_out(const __bf16* __restrict__ pw0,
                                                 const __bf16* __restrict__ pw1,
                                                 const float* __restrict__ bo,
                                                 const float* __restrict__ x,
                                                 float* __restrict__ out) {
  int i = blockIdx.x * 256 + threadIdx.x;   // 4-elem units over [B][CC][NS]
  int o = (i >> 10) & (CC - 1);             // 1024 units per channel-row
  float bias = bo[o];
  bf16_4 a = ((const bf16_4*)pw0)[i];
  bf16_4 c = ((const bf16_4*)pw1)[i];
  float4 xr = ((const float4*)x)[i];
  float4 r;
  r.x = (float)a[0] + (float)c[0] + bias + xr.x;
  r.y = (float)a[1] + (float)c[1] + bias + xr.y;
  r.z = (float)a[2] + (float)c[2] + bias + xr.z;
  r.w = (float)a[3] + (float)c[3] + bias + xr.w;
  ((float4*)out)[i] = r;
}

extern "C" void kernel_launch(void* const* d_in, const int* in_sizes, int n_in,
                              void* d_out, int out_size, void* d_ws, size_t ws_size,
                              hipStream_t stream) {
  const float* x = (const float*)d_in[0];
  const float* gamma = (const float*)d_in[1];
  const float* beta = (const float*)d_in[2];
  const float* Wq = (const float*)d_in[3];
  const float* bq = (const float*)d_in[4];
  const float* Wk = (const float*)d_in[5];
  const float* bk = (const float*)d_in[6];
  const float* Wv = (const float*)d_in[7];
  const float* bv = (const float*)d_in[8];
  const float* Wo = (const float*)d_in[9];
  const float* bo = (const float*)d_in[10];
  float* out = (float*)d_out;

  char* ws = (char*)d_ws;
  __bf16* hnT = (__bf16*)(ws + 0);           // [B][NS][CC] 8 MiB; later ao partial p0
  __bf16* qT  = (__bf16*)(ws + 8388608);     // later p1
  __bf16* kT  = (__bf16*)(ws + 16777216);    // later p2
  __bf16* vv  = (__bf16*)(ws + 25165824);    // [B][CC][NS]
  __bf16* aoT = (__bf16*)(ws + 33554432);    // [B][NS][CC]; doubles as p3 (RAW-safe)
  __bf16* Eb  = (__bf16*)(ws + 41943040);    // [B][NS][NS] 64 MiB; later wo partials
  __bf16* pw0 = (__bf16*)(ws + 41943040);    // 8 MiB (inside dead E region)
  __bf16* pw1 = (__bf16*)(ws + 50331648);    // 8 MiB
  __bf16* Wqb = (__bf16*)(ws + 109051904);   // dead after qkv -> reused as lsum
  __bf16* Wkb = (__bf16*)(ws + 109576192);
  __bf16* Wvb = (__bf16*)(ws + 110100480);
  __bf16* Wob = (__bf16*)(ws + 110624768);
  float* stats = (float*)(ws + 111149056);
  float* lsum = (float*)(ws + 109051904);    // [B][NS] fp32, aliases dead Wqb
  __bf16* p0 = hnT;
  __bf16* p1 = qT;
  __bf16* p2 = kT;
  __bf16* p3 = aoT;

  const float scale = 0.044194173824159216f;  // 512^-0.5

  cvt_w<<<1024, 256, 0, stream>>>(Wq, Wk, Wv, Wo, Wqb, Wkb, Wvb, Wob);
  gn_stats<<<BB * NGROUP, 256, 0, stream>>>(x, stats);
  gn_apply_t<<<dim3(NS / 32, CC / 32, BB), dim3(32, 8), 0, stream>>>(x, stats, gamma, beta, hnT);

  // Fused Q/K/V projections: 768 blocks (core A, double-buffered).
  qkv_gemm<<<dim3(384, 1, BB), 512, 0, stream>>>(hnT, Wqb, Wkb, Wvb, bq, bk, bv, qT, kT, vv);

  // Zero row-sum accumulator (Wqb is dead now), then E-GEMM (core B, double-buffered).
  hipMemsetAsync(lsum, 0, BB * NS * sizeof(float), stream);
  e_gemm<<<2048, 256, 0, stream>>>(qT, kT, Eb, lsum, scale);

  // aoT partials = E * v^T over quarter-K splits (1024 blocks, core A).
  ao_split4<<<1024, 512, 0, stream>>>(Eb, vv, p0, p1, p2, p3);
  reduce_ao4<<<2048, 256, 0, stream>>>(p0, p1, p2, p3, lsum, aoT);

  // Output projection split-K=2 (512 blocks, core A, bf16 partials) + fused epilogue.
  wo_split<<<dim3(NS / TILE, CC / TILE, 2 * BB), 512, 0, stream>>>(Wob, aoT, pw0, pw1);
  final_out<<<4096, 256, 0, stream>>>(pw0, pw1, bo, x, out);
}